// Round 9
// baseline (239.621 us; speedup 1.0000x reference)
//
#include <hip/hip_runtime.h>

#define N_PIX 4096
#define IMG_W 64
#define C_IN 256
#define TD3 768
#define N_B 8
#define N_G 64
#define C_OUT 256
#define KV_CHUNKS 4

typedef _Float16 f16;
typedef _Float16 half8 __attribute__((ext_vector_type(8)));
typedef _Float16 f16x4 __attribute__((ext_vector_type(4)));
typedef float f32x4 __attribute__((ext_vector_type(4)));

// ---------------------------------------------------------------------------
// k_cvt: fp32 -> f16 single plane (w_proj)
// ---------------------------------------------------------------------------
__global__ __launch_bounds__(256) void k_cvt(const float* __restrict__ a,
                                             f16* __restrict__ h, int n) {
  const int i = blockIdx.x * 256 + threadIdx.x;
  if (i < n) h[i] = (f16)a[i];
}

// ---------------------------------------------------------------------------
// k_cvt2: fp32 -> (hi, lo) f16 planes (w_qkv)
// ---------------------------------------------------------------------------
__global__ __launch_bounds__(256) void k_cvt2(const float* __restrict__ a,
                                              f16* __restrict__ h,
                                              f16* __restrict__ l, int n) {
  const int i = blockIdx.x * 256 + threadIdx.x;
  if (i < n) {
    const float v = a[i];
    const f16 x = (f16)v;
    h[i] = x;
    l[i] = (f16)(v - (float)x);
  }
}

// ---------------------------------------------------------------------------
// k_xT: x[b][256][4096] fp32 -> xT[b][4096][256] (hi,lo) f16.
// hi/lo REQUIRED: q-relu boundary + tiny attention denominators amplify
// x-rounding errors to O(1) output errors (R6/R7 post-mortem).
// ---------------------------------------------------------------------------
__global__ __launch_bounds__(256) void k_xT(const float* __restrict__ x,
                                            f16* __restrict__ xh,
                                            f16* __restrict__ xl) {
  __shared__ float st[64][65];
  const int t = threadIdx.x;
  const int n0 = blockIdx.x * 64;
  const int k0 = blockIdx.y * 64;
  const size_t b = blockIdx.z;
  const float* xb = x + b * (size_t)C_IN * N_PIX;
#pragma unroll
  for (int i = 0; i < 16; ++i) {
    const int idx = t + i * 256;
    const int r = idx >> 6, c = idx & 63;
    st[r][c] = xb[(size_t)(k0 + r) * N_PIX + n0 + c];
  }
  __syncthreads();
#pragma unroll
  for (int i = 0; i < 16; ++i) {
    const int idx = t + i * 256;
    const int n = idx >> 6, k = idx & 63;
    const float v = st[k][n];
    const f16 h = (f16)v;
    const size_t o = (b * N_PIX + n0 + n) * C_IN + k0 + k;
    xh[o] = h;
    xl[o] = (f16)(v - (float)h);
  }
}

// ---------------------------------------------------------------------------
// k_gemm3: C = (Ah+Al) * (Bh+Bl)^T, 3-term split-f16 MFMA.
// 64x64 tile, 4 waves (2x2 of 32x32), BK=32: 16 slabs x 1KB x 2 buf = 32 KB
// -> 5 blocks/CU = 20 waves/CU (occupancy was the R5/R8 limiter at 2 blocks).
// 1D grid + bijective XCD swizzle, m-tile fastest (consecutive blocks on an
// XCD share the B(x) panel; A(w) is 786 KB and stays L2-hot).
// ---------------------------------------------------------------------------
template <typename OutT>
__global__ __launch_bounds__(256) void k_gemm3(const f16* __restrict__ Ah,
                                               const f16* __restrict__ Al,
                                               const f16* __restrict__ Bh,
                                               const f16* __restrict__ Bl,
                                               OutT* __restrict__ C,
                                               int M, int K) {
  __shared__ f16 sm[2][16 * 512];  // slab = type*4 + frag: [Ah][Al][Bh][Bl]
  const int t = threadIdx.x;
  const int lane = t & 63;
  const int w = t >> 6;

  // bijective XCD swizzle (gridDim.x % 8 == 0)
  const int bid = blockIdx.x;
  const int per = gridDim.x >> 3;
  const int swz = (bid & 7) * per + (bid >> 3);
  const int mtiles = M >> 6;
  const int mt = swz % mtiles;
  const int rest = swz / mtiles;
  const int nt = rest & 63;
  const size_t bz = rest >> 6;
  const int m0 = mt * 64;
  const int n0 = nt * 64;

  const f16* Bhb = Bh + bz * (size_t)N_PIX * K;
  const f16* Blb = Bl + bz * (size_t)N_PIX * K;
  OutT* Cb = C + bz * (size_t)M * N_PIX;

  f32x4 acc[2][2];
#pragma unroll
  for (int i = 0; i < 2; ++i)
#pragma unroll
    for (int j = 0; j < 2; ++j) acc[i][j] = (f32x4){0.f, 0.f, 0.f, 0.f};

  const int wm = w >> 1, wn = w & 1;
  const int fr = lane & 15;        // row within 16-row fragment
  const int fk = (lane >> 4) * 8;  // k-octet within BK=32

  // wave w stages fragment w of each of the 4 types (slab = type*4 + w)
  const f16* gsrc[4];
  int sslot[4];
#pragma unroll
  for (int i = 0; i < 4; ++i) {
    const f16* base;
    int row0;
    if (i == 0) {
      base = Ah; row0 = m0;
    } else if (i == 1) {
      base = Al; row0 = m0;
    } else if (i == 2) {
      base = Bhb; row0 = n0;
    } else {
      base = Blb; row0 = n0;
    }
    gsrc[i] = base + (size_t)(row0 + w * 16 + fr) * K + fk;
    sslot[i] = (i * 4 + w) * 512;
  }

#pragma unroll
  for (int i = 0; i < 4; ++i)
    __builtin_amdgcn_global_load_lds(
        (const __attribute__((address_space(1))) unsigned int*)gsrc[i],
        (__attribute__((address_space(3))) unsigned int*)&sm[0][sslot[i]], 16, 0, 0);

  const int ntile = K / 32;
  int cur = 0;
  for (int tt = 0; tt < ntile; ++tt) {
    if (tt + 1 < ntile) {
#pragma unroll
      for (int i = 0; i < 4; ++i)
        __builtin_amdgcn_global_load_lds(
            (const __attribute__((address_space(1))) unsigned int*)(gsrc[i] + (tt + 1) * 32),
            (__attribute__((address_space(3))) unsigned int*)&sm[cur ^ 1][sslot[i]], 16, 0, 0);
      asm volatile("s_waitcnt vmcnt(4)" ::: "memory");
    } else {
      asm volatile("s_waitcnt vmcnt(0)" ::: "memory");
    }
    __builtin_amdgcn_s_barrier();
    const f16* smb = sm[cur];
    half8 ah[2], al[2], bh[2], bl[2];
#pragma unroll
    for (int mi = 0; mi < 2; ++mi) {
      ah[mi] = *(const half8*)&smb[(0 + wm * 2 + mi) * 512 + lane * 8];
      al[mi] = *(const half8*)&smb[(4 + wm * 2 + mi) * 512 + lane * 8];
    }
#pragma unroll
    for (int ni = 0; ni < 2; ++ni) {
      bh[ni] = *(const half8*)&smb[(8 + wn * 2 + ni) * 512 + lane * 8];
      bl[ni] = *(const half8*)&smb[(12 + wn * 2 + ni) * 512 + lane * 8];
    }
#pragma unroll
    for (int mi = 0; mi < 2; ++mi)
#pragma unroll
      for (int ni = 0; ni < 2; ++ni) {
        acc[mi][ni] = __builtin_amdgcn_mfma_f32_16x16x32_f16(ah[mi], bh[ni], acc[mi][ni], 0, 0, 0);
        acc[mi][ni] = __builtin_amdgcn_mfma_f32_16x16x32_f16(ah[mi], bl[ni], acc[mi][ni], 0, 0, 0);
        acc[mi][ni] = __builtin_amdgcn_mfma_f32_16x16x32_f16(al[mi], bh[ni], acc[mi][ni], 0, 0, 0);
      }
    __builtin_amdgcn_s_barrier();
    cur ^= 1;
  }
  const int cr = (lane >> 4) * 4;
  const int cc = lane & 15;
#pragma unroll
  for (int mi = 0; mi < 2; ++mi)
#pragma unroll
    for (int ni = 0; ni < 2; ++ni) {
      OutT* p = Cb + (size_t)(m0 + wm * 32 + mi * 16 + cr) * N_PIX + n0 + wn * 32 + ni * 16 + cc;
#pragma unroll
      for (int r = 0; r < 4; ++r) p[(size_t)r * N_PIX] = (OutT)acc[mi][ni][r];
    }
}

// ---------------------------------------------------------------------------
// k_gemm1: C = A[M][K] * B[b][4096][K]^T, single-f16 MFMA (proj: no relu/div
// downstream -> f16 rounding adds only ~1e-4 abs). 16 slabs x 2 buf = 32 KB.
// ---------------------------------------------------------------------------
template <typename OutT>
__global__ __launch_bounds__(256) void k_gemm1(const f16* __restrict__ A,
                                               const f16* __restrict__ B,
                                               OutT* __restrict__ C,
                                               int M, int K) {
  __shared__ f16 sm[2][16 * 512];
  const int t = threadIdx.x;
  const int lane = t & 63;
  const int w = t >> 6;
  const int n0 = blockIdx.x * 128;
  const int m0 = blockIdx.y * 128;
  const size_t bz = blockIdx.z;
  const f16* Bb = B + bz * (size_t)N_PIX * K;
  OutT* Cb = C + bz * (size_t)M * N_PIX;

  f32x4 acc[4][4];
#pragma unroll
  for (int i = 0; i < 4; ++i)
#pragma unroll
    for (int j = 0; j < 4; ++j) acc[i][j] = (f32x4){0.f, 0.f, 0.f, 0.f};

  const int wm = w >> 1, wn = w & 1;
  const int fr = lane & 15;
  const int fk = (lane >> 4) * 8;

  const f16* gsrc[4];
  int sslot[4];
#pragma unroll
  for (int i = 0; i < 4; ++i) {
    const int s = w + i * 4;
    const int frag = s & 7;
    const f16* base;
    int row0;
    if (s < 8) {
      base = A; row0 = m0;
    } else {
      base = Bb; row0 = n0;
    }
    gsrc[i] = base + (size_t)(row0 + frag * 16 + fr) * K + fk;
    sslot[i] = s * 512;
  }

#pragma unroll
  for (int i = 0; i < 4; ++i)
    __builtin_amdgcn_global_load_lds(
        (const __attribute__((address_space(1))) unsigned int*)gsrc[i],
        (__attribute__((address_space(3))) unsigned int*)&sm[0][sslot[i]], 16, 0, 0);

  const int nt = K / 32;
  int cur = 0;
  for (int tt = 0; tt < nt; ++tt) {
    if (tt + 1 < nt) {
#pragma unroll
      for (int i = 0; i < 4; ++i)
        __builtin_amdgcn_global_load_lds(
            (const __attribute__((address_space(1))) unsigned int*)(gsrc[i] + (tt + 1) * 32),
            (__attribute__((address_space(3))) unsigned int*)&sm[cur ^ 1][sslot[i]], 16, 0, 0);
      asm volatile("s_waitcnt vmcnt(4)" ::: "memory");
    } else {
      asm volatile("s_waitcnt vmcnt(0)" ::: "memory");
    }
    __builtin_amdgcn_s_barrier();
    const f16* smb = sm[cur];
    half8 av[4], bv[4];
#pragma unroll
    for (int mi = 0; mi < 4; ++mi) av[mi] = *(const half8*)&smb[(wm * 4 + mi) * 512 + lane * 8];
#pragma unroll
    for (int ni = 0; ni < 4; ++ni) bv[ni] = *(const half8*)&smb[(8 + wn * 4 + ni) * 512 + lane * 8];
#pragma unroll
    for (int mi = 0; mi < 4; ++mi)
#pragma unroll
      for (int ni = 0; ni < 4; ++ni)
        acc[mi][ni] = __builtin_amdgcn_mfma_f32_16x16x32_f16(av[mi], bv[ni], acc[mi][ni], 0, 0, 0);
    __builtin_amdgcn_s_barrier();
    cur ^= 1;
  }
  const int cr = (lane >> 4) * 4;
  const int cc = lane & 15;
#pragma unroll
  for (int mi = 0; mi < 4; ++mi)
#pragma unroll
    for (int ni = 0; ni < 4; ++ni) {
      OutT* p = Cb + (size_t)(m0 + wm * 64 + mi * 16 + cr) * N_PIX + n0 + wn * 64 + ni * 16 + cc;
#pragma unroll
      for (int r = 0; r < 4; ++r) p[(size_t)r * N_PIX] = (OutT)acc[mi][ni][r];
    }
}

// ---------------------------------------------------------------------------
// k_dw: depthwise 5x5. Block = (b, ch), full 64x64 plane, register window.
// ---------------------------------------------------------------------------
__global__ __launch_bounds__(256) void k_dw(const f16* __restrict__ qkv,
                                            const float* __restrict__ wdw,
                                            f16* __restrict__ dw) {
  __shared__ float sin_[68][72];
  const int t = threadIdx.x;
  const int bc = blockIdx.x;
  const int ch = bc % TD3;
  const f16* src = qkv + (size_t)bc * N_PIX;

  for (int i = t; i < 68 * 72 / 4; i += 256) ((f32x4*)sin_)[i] = (f32x4){0.f, 0.f, 0.f, 0.f};
  float wreg[25];
#pragma unroll
  for (int i = 0; i < 25; ++i) wreg[i] = wdw[(size_t)ch * 25 + i];
  __syncthreads();
  for (int i = t; i < 512; i += 256) {
    const int r = i >> 3, c8 = (i & 7) * 8;
    const half8 p = *(const half8*)(src + r * 64 + c8);
    f32x4 lo = {(float)p[0], (float)p[1], (float)p[2], (float)p[3]};
    f32x4 hi = {(float)p[4], (float)p[5], (float)p[6], (float)p[7]};
    *(f32x4*)&sin_[r + 2][c8 + 4] = lo;
    *(f32x4*)&sin_[r + 2][c8 + 8] = hi;
  }
  __syncthreads();

  const int c = t & 63;
  const int rg = t >> 6;
  const int r0 = rg * 16;
  float win[5][5];
#pragma unroll
  for (int r = 0; r < 4; ++r)
#pragma unroll
    for (int j = 0; j < 5; ++j) win[r][j] = sin_[r0 + r][c + 2 + j];
#pragma unroll
  for (int orow = 0; orow < 16; ++orow) {
    const int slot = (orow + 4) % 5;
#pragma unroll
    for (int j = 0; j < 5; ++j) win[slot][j] = sin_[r0 + orow + 4][c + 2 + j];
    float s = 0.f;
#pragma unroll
    for (int dr = 0; dr < 5; ++dr) {
      const int rs = (orow + dr) % 5;
#pragma unroll
      for (int dc = 0; dc < 5; ++dc) s = fmaf(win[rs][dc], wreg[dr * 5 + dc], s);
    }
    dw[(size_t)bc * N_PIX + (r0 + orow) * 64 + c] = (f16)s;
  }
}

// ---------------------------------------------------------------------------
// k_pw: grouped pointwise 8->8, streaming.
// ---------------------------------------------------------------------------
__global__ __launch_bounds__(256) void k_pw(const f16* __restrict__ dw,
                                            const float* __restrict__ wpw,
                                            f16* __restrict__ agg) {
  const int t = threadIdx.x;
  const int q = blockIdx.x;
  const int bg = blockIdx.y;
  const int g = bg % 96;
  float wp[64];
#pragma unroll
  for (int i = 0; i < 64; ++i) wp[i] = wpw[(size_t)g * 64 + i];
  const size_t base = ((size_t)(bg / 96) * TD3 + g * 8) * N_PIX + q * 1024;
  const int px0 = t * 4;
  float dv[8][4];
#pragma unroll
  for (int ic = 0; ic < 8; ++ic) {
    const f16x4 v = *(const f16x4*)(dw + base + (size_t)ic * N_PIX + px0);
#pragma unroll
    for (int j = 0; j < 4; ++j) dv[ic][j] = (float)v[j];
  }
#pragma unroll
  for (int oc = 0; oc < 8; ++oc) {
    f16x4 o;
#pragma unroll
    for (int j = 0; j < 4; ++j) {
      float s = 0.f;
#pragma unroll
      for (int ic = 0; ic < 8; ++ic) s = fmaf(dv[ic][j], wp[oc * 8 + ic], s);
      o[j] = (f16)s;
    }
    *(f16x4*)(agg + base + (size_t)oc * N_PIX + px0) = o;
  }
}

// ---------------------------------------------------------------------------
// k_kv: chunked kv partial sums (deterministic), f16 in, fp32 accumulate
// ---------------------------------------------------------------------------
__global__ __launch_bounds__(256) void k_kv(const f16* __restrict__ qkv,
                                            const f16* __restrict__ agg,
                                            float* __restrict__ kvbuf) {
  const int t = threadIdx.x;
  const int chunk = blockIdx.x;
  const int g = blockIdx.y;
  const int b = blockIdx.z;
  const f16* src = (g < 32) ? qkv : agg;
  const int base = (g & 31) * 24;
  const f16* kc = src + ((size_t)b * TD3 + base + 8) * N_PIX;
  const f16* vc = src + ((size_t)b * TD3 + base + 16) * N_PIX;

  float acc[72];
#pragma unroll
  for (int i = 0; i < 72; i++) acc[i] = 0.f;

  const int n0 = chunk * (N_PIX / KV_CHUNKS);
  for (int i = 0; i < (N_PIX / KV_CHUNKS) / 256; i++) {
    const int n = n0 + t + i * 256;
    float kd[8], ve[8];
#pragma unroll
    for (int d = 0; d < 8; d++) kd[d] = fmaxf((float)kc[(size_t)d * N_PIX + n], 0.f);
#pragma unroll
    for (int e = 0; e < 8; e++) ve[e] = (float)vc[(size_t)e * N_PIX + n];
#pragma unroll
    for (int d = 0; d < 8; d++) {
#pragma unroll
      for (int e = 0; e < 8; e++) acc[d * 9 + e] = fmaf(kd[d], ve[e], acc[d * 9 + e]);
      acc[d * 9 + 8] += kd[d];
    }
  }
#pragma unroll
  for (int i = 0; i < 72; i++) {
    float v = acc[i];
#pragma unroll
    for (int off = 32; off > 0; off >>= 1) v += __shfl_down(v, off, 64);
    acc[i] = v;
  }
  __shared__ float red[4][72];
  const int lane = t & 63, wv = t >> 6;
  if (lane == 0) {
#pragma unroll
    for (int i = 0; i < 72; i++) red[wv][i] = acc[i];
  }
  __syncthreads();
  if (t < 72) {
    const float s = red[0][t] + red[1][t] + red[2][t] + red[3][t];
    kvbuf[(((size_t)chunk * N_B + b) * N_G + g) * 72 + t] = s;
  }
}

// ---------------------------------------------------------------------------
// k_kvsum: sum the 4 chunk partials -> kvsum[b][g][72]
// ---------------------------------------------------------------------------
__global__ __launch_bounds__(256) void k_kvsum(const float* __restrict__ kvbuf,
                                               float* __restrict__ kvsum) {
  const int i = blockIdx.x * 256 + threadIdx.x;
  float s = 0.f;
#pragma unroll
  for (int c = 0; c < KV_CHUNKS; c++) s += kvbuf[(size_t)c * (N_B * N_G * 72) + i];
  kvsum[i] = s;
}

// ---------------------------------------------------------------------------
// k_att: att^T[b][4096][512] f16 single plane (proj side tolerates f16).
// ---------------------------------------------------------------------------
__global__ __launch_bounds__(256) void k_att(const f16* __restrict__ qkvh,
                                             const f16* __restrict__ aggh,
                                             const float* __restrict__ kvsum,
                                             f16* __restrict__ atth) {
  __shared__ float skv[N_G * 72];
  __shared__ f16 sa[512][34];
  const int t = threadIdx.x;
  const int n0 = blockIdx.x * 32;
  const size_t b = blockIdx.y;
  for (int i = t; i < N_G * 72; i += 256) skv[i] = kvsum[b * (N_G * 72) + i];
  __syncthreads();
  const int px = t & 31, gq = t >> 5;
#pragma unroll
  for (int gi = 0; gi < 8; ++gi) {
    const int g = gq * 8 + gi;
    const f16* src = (g < 32) ? qkvh : aggh;
    const int base = (g & 31) * 24;
    const f16* qc = src + ((size_t)b * TD3 + base) * N_PIX + n0 + px;
    float num[8] = {0.f, 0.f, 0.f, 0.f, 0.f, 0.f, 0.f, 0.f};
    float den = 0.f;
#pragma unroll
    for (int d = 0; d < 8; ++d) {
      const float qd = fmaxf((float)qc[(size_t)d * N_PIX], 0.f);
      const float* kvg = &skv[g * 72 + d * 9];
#pragma unroll
      for (int e = 0; e < 8; ++e) num[e] = fmaf(qd, kvg[e], num[e]);
      den = fmaf(qd, kvg[8], den);
    }
    const float rd = 1.f / (den + 1e-15f);
#pragma unroll
    for (int e = 0; e < 8; ++e) sa[g * 8 + e][px] = (f16)(num[e] * rd);
  }
  __syncthreads();
  f16* dst = atth + (b * N_PIX + n0) * 512;
  for (int i = 0; i < 64; ++i) {
    const int idx = t + i * 256;
    dst[idx] = sa[idx & 511][idx >> 9];
  }
}

// ---------------------------------------------------------------------------
extern "C" void kernel_launch(void* const* d_in, const int* in_sizes, int n_in,
                              void* d_out, int out_size, void* d_ws, size_t ws_size,
                              hipStream_t stream) {
  const float* x = (const float*)d_in[0];
  const float* w_qkv = (const float*)d_in[1];
  const float* w_dw = (const float*)d_in[2];
  const float* w_pw = (const float*)d_in[3];
  const float* w_proj = (const float*)d_in[4];
  float* out = (float*)d_out;

  char* ws = (char*)d_ws;
  size_t off = 0;
  f16* qkvh = (f16*)(ws + off); off += (size_t)N_B * TD3 * N_PIX * 2;  // 50.3 MB
  f16* aggh = (f16*)(ws + off); off += (size_t)N_B * TD3 * N_PIX * 2;  // 50.3 MB
  float* kvbuf = (float*)(ws + off); off += (size_t)KV_CHUNKS * N_B * N_G * 72 * 4;
  float* kvsum = (float*)(ws + off); off += (size_t)N_B * N_G * 72 * 4;
  f16* wqh = (f16*)(ws + off); off += (size_t)TD3 * C_IN * 2;
  f16* wql = (f16*)(ws + off); off += (size_t)TD3 * C_IN * 2;
  f16* wph = (f16*)(ws + off); off += (size_t)C_OUT * 512 * 2;
  // union region (disjoint lifetimes): xT(hi,lo) -> dwbuf -> attT(single)
  f16* xTh = (f16*)(ws + off);
  f16* xTl = xTh + (size_t)N_B * N_PIX * C_IN;
  f16* dwbuf = (f16*)(ws + off);
  f16* atth = (f16*)(ws + off);

  k_cvt2<<<dim3((TD3 * C_IN + 255) / 256), 256, 0, stream>>>(w_qkv, wqh, wql, TD3 * C_IN);
  k_cvt<<<dim3((C_OUT * 512 + 255) / 256), 256, 0, stream>>>(w_proj, wph, C_OUT * 512);
  k_xT<<<dim3(N_PIX / 64, C_IN / 64, N_B), 256, 0, stream>>>(x, xTh, xTl);
  // grid: 12 m-tiles x 64 n-tiles x 8 batches = 6144 (bijective XCD swizzle inside)
  k_gemm3<f16><<<dim3((TD3 / 64) * (N_PIX / 64) * N_B), 256, 0, stream>>>(
      wqh, wql, xTh, xTl, qkvh, TD3, C_IN);
  k_dw<<<dim3(N_B * TD3), 256, 0, stream>>>(qkvh, w_dw, dwbuf);
  k_pw<<<dim3(4, N_B * 96), 256, 0, stream>>>(dwbuf, w_pw, aggh);
  k_kv<<<dim3(KV_CHUNKS, N_G, N_B), 256, 0, stream>>>(qkvh, aggh, kvbuf);
  k_kvsum<<<dim3(N_B * N_G * 72 / 256), 256, 0, stream>>>(kvbuf, kvsum);
  k_att<<<dim3(N_PIX / 32, N_B), 256, 0, stream>>>(qkvh, aggh, kvsum, atth);
  k_gemm1<float><<<dim3(N_PIX / 128, C_OUT / 128, N_B), 256, 0, stream>>>(
      wph, atth, out, C_OUT, 512);
}

// Round 10
// 227.519 us; speedup vs baseline: 1.0532x; 1.0532x over previous
//
#include <hip/hip_runtime.h>

#define N_PIX 4096
#define IMG_W 64
#define C_IN 256
#define TD3 768
#define N_B 8
#define N_G 64
#define C_OUT 256
#define KV_CHUNKS 4

typedef _Float16 f16;
typedef _Float16 half8 __attribute__((ext_vector_type(8)));
typedef _Float16 f16x4 __attribute__((ext_vector_type(4)));
typedef _Float16 f16x2 __attribute__((ext_vector_type(2)));
typedef float f32x4 __attribute__((ext_vector_type(4)));

// ---------------------------------------------------------------------------
// k_cvtw: one launch converts both weight tensors.
// w_qkv -> (hi,lo) f16 planes; w_proj -> single f16.
// ---------------------------------------------------------------------------
__global__ __launch_bounds__(256) void k_cvtw(const float* __restrict__ wq,
                                              const float* __restrict__ wp,
                                              f16* __restrict__ wqh,
                                              f16* __restrict__ wql,
                                              f16* __restrict__ wph) {
  const int i = blockIdx.x * 256 + threadIdx.x;
  if (i < TD3 * C_IN) {
    const float v = wq[i];
    const f16 h = (f16)v;
    wqh[i] = h;
    wql[i] = (f16)(v - (float)h);
  } else if (i < TD3 * C_IN + C_OUT * 512) {
    const int j = i - TD3 * C_IN;
    wph[j] = (f16)wp[j];
  }
}

// ---------------------------------------------------------------------------
// k_xT: x[b][256][4096] fp32 -> xT[b][4096][256] (hi,lo) f16.
// hi/lo REQUIRED: q-relu boundary + tiny attention denominators amplify
// x-rounding errors to O(1) output errors (R6/R7 post-mortem).
// ---------------------------------------------------------------------------
__global__ __launch_bounds__(256) void k_xT(const float* __restrict__ x,
                                            f16* __restrict__ xh,
                                            f16* __restrict__ xl) {
  __shared__ float st[64][65];
  const int t = threadIdx.x;
  const int n0 = blockIdx.x * 64;
  const int k0 = blockIdx.y * 64;
  const size_t b = blockIdx.z;
  const float* xb = x + b * (size_t)C_IN * N_PIX;
#pragma unroll
  for (int i = 0; i < 16; ++i) {
    const int idx = t + i * 256;
    const int r = idx >> 6, c = idx & 63;
    st[r][c] = xb[(size_t)(k0 + r) * N_PIX + n0 + c];
  }
  __syncthreads();
#pragma unroll
  for (int i = 0; i < 16; ++i) {
    const int idx = t + i * 256;
    const int n = idx >> 6, k = idx & 63;
    const float v = st[k][n];
    const f16 h = (f16)v;
    const size_t o = (b * N_PIX + n0 + n) * C_IN + k0 + k;
    xh[o] = h;
    xl[o] = (f16)(v - (float)h);
  }
}

// ---------------------------------------------------------------------------
// k_gemm3: C = (Ah+Al) * (Bh+Bl)^T, 3-term split-f16 MFMA.
// R8-proven 128x128 tile, 4 waves, BK=32, 32 slabs x 2 buf = 64 KB, counted
// vmcnt. (R9 lesson: 64x64 tile = sync-dominated, 1.7x SLOWER despite 2.5x
// occupancy — compute-per-barrier is the binding ratio; keep 128x128.)
// 1D grid + bijective XCD swizzle, m-tile fastest: consecutive blocks on one
// XCD reuse the same 128-row x-panel 6x; w panels (786 KB) stay L2-resident.
// ---------------------------------------------------------------------------
template <typename OutT>
__global__ __launch_bounds__(256) void k_gemm3(const f16* __restrict__ Ah,
                                               const f16* __restrict__ Al,
                                               const f16* __restrict__ Bh,
                                               const f16* __restrict__ Bl,
                                               OutT* __restrict__ C,
                                               int M, int K) {
  __shared__ f16 sm[2][32 * 512];
  const int t = threadIdx.x;
  const int lane = t & 63;
  const int w = t >> 6;

  // bijective XCD swizzle (gridDim.x % 8 == 0), m-tile fastest
  const int per = gridDim.x >> 3;
  const int swz = (blockIdx.x & 7) * per + (blockIdx.x >> 3);
  const int mtiles = M >> 7;
  const int mt = swz % mtiles;
  const int rest = swz / mtiles;
  const int nt = rest & 31;
  const size_t bz = rest >> 5;
  const int m0 = mt * 128;
  const int n0 = nt * 128;

  const f16* Bhb = Bh + bz * (size_t)N_PIX * K;
  const f16* Blb = Bl + bz * (size_t)N_PIX * K;
  OutT* Cb = C + bz * (size_t)M * N_PIX;

  f32x4 acc[4][4];
#pragma unroll
  for (int i = 0; i < 4; ++i)
#pragma unroll
    for (int j = 0; j < 4; ++j) acc[i][j] = (f32x4){0.f, 0.f, 0.f, 0.f};

  const int wm = w >> 1, wn = w & 1;
  const int fr = lane & 15;
  const int fk = (lane >> 4) * 8;

  const f16* gsrc[8];
  int sslot[8];
#pragma unroll
  for (int i = 0; i < 8; ++i) {
    const int s = w + i * 4;
    const int frag = s & 7;
    const f16* base;
    int row0;
    if (s < 8) {
      base = Ah; row0 = m0;
    } else if (s < 16) {
      base = Al; row0 = m0;
    } else if (s < 24) {
      base = Bhb; row0 = n0;
    } else {
      base = Blb; row0 = n0;
    }
    gsrc[i] = base + (size_t)(row0 + frag * 16 + fr) * K + fk;
    sslot[i] = s * 512;
  }

#pragma unroll
  for (int i = 0; i < 8; ++i)
    __builtin_amdgcn_global_load_lds(
        (const __attribute__((address_space(1))) unsigned int*)gsrc[i],
        (__attribute__((address_space(3))) unsigned int*)&sm[0][sslot[i]], 16, 0, 0);

  const int ntk = K / 32;
  int cur = 0;
  for (int tt = 0; tt < ntk; ++tt) {
    if (tt + 1 < ntk) {
#pragma unroll
      for (int i = 0; i < 8; ++i)
        __builtin_amdgcn_global_load_lds(
            (const __attribute__((address_space(1))) unsigned int*)(gsrc[i] + (tt + 1) * 32),
            (__attribute__((address_space(3))) unsigned int*)&sm[cur ^ 1][sslot[i]], 16, 0, 0);
      asm volatile("s_waitcnt vmcnt(8)" ::: "memory");
    } else {
      asm volatile("s_waitcnt vmcnt(0)" ::: "memory");
    }
    __builtin_amdgcn_s_barrier();
    const f16* smb = sm[cur];
    half8 ah[4], al[4], bh[4], bl[4];
#pragma unroll
    for (int mi = 0; mi < 4; ++mi) {
      ah[mi] = *(const half8*)&smb[(wm * 4 + mi) * 512 + lane * 8];
      al[mi] = *(const half8*)&smb[(8 + wm * 4 + mi) * 512 + lane * 8];
    }
#pragma unroll
    for (int ni = 0; ni < 4; ++ni) {
      bh[ni] = *(const half8*)&smb[(16 + wn * 4 + ni) * 512 + lane * 8];
      bl[ni] = *(const half8*)&smb[(24 + wn * 4 + ni) * 512 + lane * 8];
    }
#pragma unroll
    for (int mi = 0; mi < 4; ++mi)
#pragma unroll
      for (int ni = 0; ni < 4; ++ni) {
        acc[mi][ni] = __builtin_amdgcn_mfma_f32_16x16x32_f16(ah[mi], bh[ni], acc[mi][ni], 0, 0, 0);
        acc[mi][ni] = __builtin_amdgcn_mfma_f32_16x16x32_f16(ah[mi], bl[ni], acc[mi][ni], 0, 0, 0);
        acc[mi][ni] = __builtin_amdgcn_mfma_f32_16x16x32_f16(al[mi], bh[ni], acc[mi][ni], 0, 0, 0);
      }
    __builtin_amdgcn_s_barrier();
    cur ^= 1;
  }
  const int cr = (lane >> 4) * 4;
  const int cc = lane & 15;
#pragma unroll
  for (int mi = 0; mi < 4; ++mi)
#pragma unroll
    for (int ni = 0; ni < 4; ++ni) {
      OutT* p = Cb + (size_t)(m0 + wm * 64 + mi * 16 + cr) * N_PIX + n0 + wn * 64 + ni * 16 + cc;
#pragma unroll
      for (int r = 0; r < 4; ++r) p[(size_t)r * N_PIX] = (OutT)acc[mi][ni][r];
    }
}

// ---------------------------------------------------------------------------
// k_gemm1: C = A[M][K] * B[b][4096][K]^T, single-f16 MFMA (proj: no relu/div
// downstream -> f16 rounding adds only ~1e-4 abs). 16 slabs x 2 buf = 32 KB.
// ---------------------------------------------------------------------------
template <typename OutT>
__global__ __launch_bounds__(256) void k_gemm1(const f16* __restrict__ A,
                                               const f16* __restrict__ B,
                                               OutT* __restrict__ C,
                                               int M, int K) {
  __shared__ f16 sm[2][16 * 512];
  const int t = threadIdx.x;
  const int lane = t & 63;
  const int w = t >> 6;
  const int n0 = blockIdx.x * 128;
  const int m0 = blockIdx.y * 128;
  const size_t bz = blockIdx.z;
  const f16* Bb = B + bz * (size_t)N_PIX * K;
  OutT* Cb = C + bz * (size_t)M * N_PIX;

  f32x4 acc[4][4];
#pragma unroll
  for (int i = 0; i < 4; ++i)
#pragma unroll
    for (int j = 0; j < 4; ++j) acc[i][j] = (f32x4){0.f, 0.f, 0.f, 0.f};

  const int wm = w >> 1, wn = w & 1;
  const int fr = lane & 15;
  const int fk = (lane >> 4) * 8;

  const f16* gsrc[4];
  int sslot[4];
#pragma unroll
  for (int i = 0; i < 4; ++i) {
    const int s = w + i * 4;
    const int frag = s & 7;
    const f16* base;
    int row0;
    if (s < 8) {
      base = A; row0 = m0;
    } else {
      base = Bb; row0 = n0;
    }
    gsrc[i] = base + (size_t)(row0 + frag * 16 + fr) * K + fk;
    sslot[i] = s * 512;
  }

#pragma unroll
  for (int i = 0; i < 4; ++i)
    __builtin_amdgcn_global_load_lds(
        (const __attribute__((address_space(1))) unsigned int*)gsrc[i],
        (__attribute__((address_space(3))) unsigned int*)&sm[0][sslot[i]], 16, 0, 0);

  const int nt = K / 32;
  int cur = 0;
  for (int tt = 0; tt < nt; ++tt) {
    if (tt + 1 < nt) {
#pragma unroll
      for (int i = 0; i < 4; ++i)
        __builtin_amdgcn_global_load_lds(
            (const __attribute__((address_space(1))) unsigned int*)(gsrc[i] + (tt + 1) * 32),
            (__attribute__((address_space(3))) unsigned int*)&sm[cur ^ 1][sslot[i]], 16, 0, 0);
      asm volatile("s_waitcnt vmcnt(4)" ::: "memory");
    } else {
      asm volatile("s_waitcnt vmcnt(0)" ::: "memory");
    }
    __builtin_amdgcn_s_barrier();
    const f16* smb = sm[cur];
    half8 av[4], bv[4];
#pragma unroll
    for (int mi = 0; mi < 4; ++mi) av[mi] = *(const half8*)&smb[(wm * 4 + mi) * 512 + lane * 8];
#pragma unroll
    for (int ni = 0; ni < 4; ++ni) bv[ni] = *(const half8*)&smb[(8 + wn * 4 + ni) * 512 + lane * 8];
#pragma unroll
    for (int mi = 0; mi < 4; ++mi)
#pragma unroll
      for (int ni = 0; ni < 4; ++ni)
        acc[mi][ni] = __builtin_amdgcn_mfma_f32_16x16x32_f16(av[mi], bv[ni], acc[mi][ni], 0, 0, 0);
    __builtin_amdgcn_s_barrier();
    cur ^= 1;
  }
  const int cr = (lane >> 4) * 4;
  const int cc = lane & 15;
#pragma unroll
  for (int mi = 0; mi < 4; ++mi)
#pragma unroll
    for (int ni = 0; ni < 4; ++ni) {
      OutT* p = Cb + (size_t)(m0 + wm * 64 + mi * 16 + cr) * N_PIX + n0 + wn * 64 + ni * 16 + cc;
#pragma unroll
      for (int r = 0; r < 4; ++r) p[(size_t)r * N_PIX] = (OutT)acc[mi][ni][r];
    }
}

// ---------------------------------------------------------------------------
// k_agg: FUSED depthwise 5x5 + grouped pointwise 8->8.
// Block = (32x32 tile, b*96+g). LDS: f16 halo 8x36x36 (20.7 KB) + f16 dw
// buffer 8x1024 (16 KB) = 36.7 KB -> 4 blocks/CU (fixes R3's 74 KB / 2-block
// occupancy trap). Saves the 100 MB dw global round-trip.
// Rounding path (f32 math, f16 intermediate) identical to split k_dw->k_pw.
// ---------------------------------------------------------------------------
__global__ __launch_bounds__(256) void k_agg(const f16* __restrict__ qkv,
                                             const float* __restrict__ wdw,
                                             const float* __restrict__ wpw,
                                             f16* __restrict__ agg) {
  __shared__ f16 halo[8][36][36];
  __shared__ f16 dwb[8][1024];
  const int t = threadIdx.x;
  const int tile = blockIdx.x;
  const int tx0 = (tile & 1) * 32;
  const int ty0 = (tile >> 1) * 32;
  const int bg = blockIdx.y;
  const int b = bg / 96, g = bg % 96;
  const f16* src = qkv + ((size_t)b * TD3 + g * 8) * N_PIX;

  // stage halo as f16x2 pairs (pair starts even -> never partially OOB in x)
  for (int idx = t; idx < 8 * 36 * 18; idx += 256) {
    const int ch = idx / (36 * 18);
    const int r = idx - ch * (36 * 18);
    const int ir = r / 18, ip = r - ir * 18;
    const int y = ty0 + ir - 2;
    const int x = tx0 + ip * 2 - 2;
    f16x2 p = {(f16)0.f, (f16)0.f};
    if (y >= 0 && y < IMG_W && x >= 0 && x < IMG_W)
      p = *(const f16x2*)(src + (size_t)ch * N_PIX + y * IMG_W + x);
    *(f16x2*)&halo[ch][ir][ip * 2] = p;
  }

  const int ch = t >> 5;
  const int c = t & 31;
  float wreg[25];
#pragma unroll
  for (int i = 0; i < 25; ++i) wreg[i] = wdw[(size_t)(g * 8 + ch) * 25 + i];
  __syncthreads();

  // phase 1: depthwise 5x5, register sliding window (5 reads/row)
  float win[5][5];
#pragma unroll
  for (int r = 0; r < 4; ++r)
#pragma unroll
    for (int j = 0; j < 5; ++j) win[r][j] = (float)halo[ch][r][c + j];
#pragma unroll
  for (int orow = 0; orow < 32; ++orow) {
    const int slot = (orow + 4) % 5;
#pragma unroll
    for (int j = 0; j < 5; ++j) win[slot][j] = (float)halo[ch][orow + 4][c + j];
    float s = 0.f;
#pragma unroll
    for (int dr = 0; dr < 5; ++dr) {
      const int rs = (orow + dr) % 5;
#pragma unroll
      for (int dc = 0; dc < 5; ++dc) s = fmaf(win[rs][dc], wreg[dr * 5 + dc], s);
    }
    dwb[ch][orow * 32 + c] = (f16)s;
  }

  // phase 2: grouped pointwise 8->8 from LDS dw buffer
  float wp[64];
#pragma unroll
  for (int i = 0; i < 64; ++i) wp[i] = wpw[(size_t)g * 64 + i];
  __syncthreads();
  f16* dst = agg + ((size_t)b * TD3 + g * 8) * N_PIX;
  const int p = t * 4;
  const int pr = p >> 5, pc = p & 31;
  float dv[8][4];
#pragma unroll
  for (int ic = 0; ic < 8; ++ic) {
    const f16x4 v = *(const f16x4*)&dwb[ic][p];
#pragma unroll
    for (int j = 0; j < 4; ++j) dv[ic][j] = (float)v[j];
  }
  const size_t o = (size_t)(ty0 + pr) * IMG_W + tx0 + pc;
#pragma unroll
  for (int oc = 0; oc < 8; ++oc) {
    f16x4 ov;
#pragma unroll
    for (int j = 0; j < 4; ++j) {
      float s = 0.f;
#pragma unroll
      for (int ic = 0; ic < 8; ++ic) s = fmaf(dv[ic][j], wp[oc * 8 + ic], s);
      ov[j] = (f16)s;
    }
    *(f16x4*)(dst + (size_t)oc * N_PIX + o) = ov;
  }
}

// ---------------------------------------------------------------------------
// k_kv: chunked kv partial sums (deterministic), f16 in, fp32 accumulate
// ---------------------------------------------------------------------------
__global__ __launch_bounds__(256) void k_kv(const f16* __restrict__ qkv,
                                            const f16* __restrict__ agg,
                                            float* __restrict__ kvbuf) {
  const int t = threadIdx.x;
  const int chunk = blockIdx.x;
  const int g = blockIdx.y;
  const int b = blockIdx.z;
  const f16* src = (g < 32) ? qkv : agg;
  const int base = (g & 31) * 24;
  const f16* kc = src + ((size_t)b * TD3 + base + 8) * N_PIX;
  const f16* vc = src + ((size_t)b * TD3 + base + 16) * N_PIX;

  float acc[72];
#pragma unroll
  for (int i = 0; i < 72; i++) acc[i] = 0.f;

  const int n0 = chunk * (N_PIX / KV_CHUNKS);
  for (int i = 0; i < (N_PIX / KV_CHUNKS) / 256; i++) {
    const int n = n0 + t + i * 256;
    float kd[8], ve[8];
#pragma unroll
    for (int d = 0; d < 8; d++) kd[d] = fmaxf((float)kc[(size_t)d * N_PIX + n], 0.f);
#pragma unroll
    for (int e = 0; e < 8; e++) ve[e] = (float)vc[(size_t)e * N_PIX + n];
#pragma unroll
    for (int d = 0; d < 8; d++) {
#pragma unroll
      for (int e = 0; e < 8; e++) acc[d * 9 + e] = fmaf(kd[d], ve[e], acc[d * 9 + e]);
      acc[d * 9 + 8] += kd[d];
    }
  }
#pragma unroll
  for (int i = 0; i < 72; i++) {
    float v = acc[i];
#pragma unroll
    for (int off = 32; off > 0; off >>= 1) v += __shfl_down(v, off, 64);
    acc[i] = v;
  }
  __shared__ float red[4][72];
  const int lane = t & 63, wv = t >> 6;
  if (lane == 0) {
#pragma unroll
    for (int i = 0; i < 72; i++) red[wv][i] = acc[i];
  }
  __syncthreads();
  if (t < 72) {
    const float s = red[0][t] + red[1][t] + red[2][t] + red[3][t];
    kvbuf[(((size_t)chunk * N_B + b) * N_G + g) * 72 + t] = s;
  }
}

// ---------------------------------------------------------------------------
// k_att: att^T[b][4096][512] f16; sums the kv chunk partials inline (same
// order as old k_kvsum -> bit-identical, one launch saved).
// ---------------------------------------------------------------------------
__global__ __launch_bounds__(256) void k_att(const f16* __restrict__ qkvh,
                                             const f16* __restrict__ aggh,
                                             const float* __restrict__ kvbuf,
                                             f16* __restrict__ atth) {
  __shared__ float skv[N_G * 72];
  __shared__ f16 sa[512][34];
  const int t = threadIdx.x;
  const int n0 = blockIdx.x * 32;
  const size_t b = blockIdx.y;
  for (int i = t; i < N_G * 72; i += 256) {
    float s = 0.f;
#pragma unroll
    for (int c = 0; c < KV_CHUNKS; c++)
      s += kvbuf[(size_t)c * (N_B * N_G * 72) + b * (N_G * 72) + i];
    skv[i] = s;
  }
  __syncthreads();
  const int px = t & 31, gq = t >> 5;
#pragma unroll
  for (int gi = 0; gi < 8; ++gi) {
    const int g = gq * 8 + gi;
    const f16* src = (g < 32) ? qkvh : aggh;
    const int base = (g & 31) * 24;
    const f16* qc = src + ((size_t)b * TD3 + base) * N_PIX + n0 + px;
    float num[8] = {0.f, 0.f, 0.f, 0.f, 0.f, 0.f, 0.f, 0.f};
    float den = 0.f;
#pragma unroll
    for (int d = 0; d < 8; ++d) {
      const float qd = fmaxf((float)qc[(size_t)d * N_PIX], 0.f);
      const float* kvg = &skv[g * 72 + d * 9];
#pragma unroll
      for (int e = 0; e < 8; ++e) num[e] = fmaf(qd, kvg[e], num[e]);
      den = fmaf(qd, kvg[8], den);
    }
    const float rd = 1.f / (den + 1e-15f);
#pragma unroll
    for (int e = 0; e < 8; ++e) sa[g * 8 + e][px] = (f16)(num[e] * rd);
  }
  __syncthreads();
  f16* dst = atth + (b * N_PIX + n0) * 512;
  for (int i = 0; i < 64; ++i) {
    const int idx = t + i * 256;
    dst[idx] = sa[idx & 511][idx >> 9];
  }
}

// ---------------------------------------------------------------------------
extern "C" void kernel_launch(void* const* d_in, const int* in_sizes, int n_in,
                              void* d_out, int out_size, void* d_ws, size_t ws_size,
                              hipStream_t stream) {
  const float* x = (const float*)d_in[0];
  const float* w_qkv = (const float*)d_in[1];
  const float* w_dw = (const float*)d_in[2];
  const float* w_pw = (const float*)d_in[3];
  const float* w_proj = (const float*)d_in[4];
  float* out = (float*)d_out;

  char* ws = (char*)d_ws;
  size_t off = 0;
  f16* qkvh = (f16*)(ws + off); off += (size_t)N_B * TD3 * N_PIX * 2;  // 50.3 MB
  f16* aggh = (f16*)(ws + off); off += (size_t)N_B * TD3 * N_PIX * 2;  // 50.3 MB
  float* kvbuf = (float*)(ws + off); off += (size_t)KV_CHUNKS * N_B * N_G * 72 * 4;
  f16* wqh = (f16*)(ws + off); off += (size_t)TD3 * C_IN * 2;
  f16* wql = (f16*)(ws + off); off += (size_t)TD3 * C_IN * 2;
  f16* wph = (f16*)(ws + off); off += (size_t)C_OUT * 512 * 2;
  // union region (disjoint lifetimes): xT(hi,lo) -> attT(single)
  f16* xTh = (f16*)(ws + off);
  f16* xTl = xTh + (size_t)N_B * N_PIX * C_IN;
  f16* atth = (f16*)(ws + off);

  const int ncvt = (TD3 * C_IN + C_OUT * 512 + 255) / 256;
  k_cvtw<<<dim3(ncvt), 256, 0, stream>>>(w_qkv, w_proj, wqh, wql, wph);
  k_xT<<<dim3(N_PIX / 64, C_IN / 64, N_B), 256, 0, stream>>>(x, xTh, xTl);
  // grid: 6 m-tiles x 32 n-tiles x 8 batches = 1536 (XCD swizzle inside)
  k_gemm3<f16><<<dim3((TD3 / 128) * (N_PIX / 128) * N_B), 256, 0, stream>>>(
      wqh, wql, xTh, xTl, qkvh, TD3, C_IN);
  k_agg<<<dim3(4, N_B * 96), 256, 0, stream>>>(qkvh, w_dw, w_pw, aggh);
  k_kv<<<dim3(KV_CHUNKS, N_G, N_B), 256, 0, stream>>>(qkvh, aggh, kvbuf);
  k_att<<<dim3(N_PIX / 32, N_B), 256, 0, stream>>>(qkvh, aggh, kvbuf, atth);
  k_gemm1<float><<<dim3(N_PIX / 128, C_OUT / 128, N_B), 256, 0, stream>>>(
      wph, atth, out, C_OUT, 512);
}

// Round 11
// 197.886 us; speedup vs baseline: 1.2109x; 1.1497x over previous
//
#include <hip/hip_runtime.h>

#define N_PIX 4096
#define IMG_W 64
#define C_IN 256
#define TD3 768
#define N_B 8
#define N_G 64
#define C_OUT 256
#define KV_CHUNKS 4

typedef _Float16 f16;
typedef _Float16 half8 __attribute__((ext_vector_type(8)));
typedef _Float16 f16x4 __attribute__((ext_vector_type(4)));
typedef float f32x4 __attribute__((ext_vector_type(4)));

// ---------------------------------------------------------------------------
// k_cvtw: one launch converts both weight tensors.
// w_qkv -> (hi,lo) f16 planes; w_proj -> single f16.
// ---------------------------------------------------------------------------
__global__ __launch_bounds__(256) void k_cvtw(const float* __restrict__ wq,
                                              const float* __restrict__ wp,
                                              f16* __restrict__ wqh,
                                              f16* __restrict__ wql,
                                              f16* __restrict__ wph) {
  const int i = blockIdx.x * 256 + threadIdx.x;
  if (i < TD3 * C_IN) {
    const float v = wq[i];
    const f16 h = (f16)v;
    wqh[i] = h;
    wql[i] = (f16)(v - (float)h);
  } else if (i < TD3 * C_IN + C_OUT * 512) {
    const int j = i - TD3 * C_IN;
    wph[j] = (f16)wp[j];
  }
}

// ---------------------------------------------------------------------------
// k_xT: x[b][256][4096] fp32 -> xT[b][4096][256] (hi,lo) f16.
// hi/lo REQUIRED: q-relu boundary + tiny attention denominators amplify
// x-rounding errors to O(1) output errors (R6/R7 post-mortem).
// ---------------------------------------------------------------------------
__global__ __launch_bounds__(256) void k_xT(const float* __restrict__ x,
                                            f16* __restrict__ xh,
                                            f16* __restrict__ xl) {
  __shared__ float st[64][65];
  const int t = threadIdx.x;
  const int n0 = blockIdx.x * 64;
  const int k0 = blockIdx.y * 64;
  const size_t b = blockIdx.z;
  const float* xb = x + b * (size_t)C_IN * N_PIX;
#pragma unroll
  for (int i = 0; i < 16; ++i) {
    const int idx = t + i * 256;
    const int r = idx >> 6, c = idx & 63;
    st[r][c] = xb[(size_t)(k0 + r) * N_PIX + n0 + c];
  }
  __syncthreads();
#pragma unroll
  for (int i = 0; i < 16; ++i) {
    const int idx = t + i * 256;
    const int n = idx >> 6, k = idx & 63;
    const float v = st[k][n];
    const f16 h = (f16)v;
    const size_t o = (b * N_PIX + n0 + n) * C_IN + k0 + k;
    xh[o] = h;
    xl[o] = (f16)(v - (float)h);
  }
}

// ---------------------------------------------------------------------------
// k_gemm3: C = (Ah+Al) * (Bh+Bl)^T, 3-term split-f16 MFMA.
// R8-proven 128x128 tile, 4 waves, BK=32, 32 slabs x 2 buf = 64 KB, counted
// vmcnt. (R9 lesson: 64x64 tile is sync-dominated — keep 128x128.)
// 1D grid + bijective XCD swizzle, m-tile fastest (R10: worth ~14 µs).
// ---------------------------------------------------------------------------
template <typename OutT>
__global__ __launch_bounds__(256) void k_gemm3(const f16* __restrict__ Ah,
                                               const f16* __restrict__ Al,
                                               const f16* __restrict__ Bh,
                                               const f16* __restrict__ Bl,
                                               OutT* __restrict__ C,
                                               int M, int K) {
  __shared__ f16 sm[2][32 * 512];
  const int t = threadIdx.x;
  const int lane = t & 63;
  const int w = t >> 6;

  // bijective XCD swizzle (gridDim.x % 8 == 0), m-tile fastest
  const int per = gridDim.x >> 3;
  const int swz = (blockIdx.x & 7) * per + (blockIdx.x >> 3);
  const int mtiles = M >> 7;
  const int mt = swz % mtiles;
  const int rest = swz / mtiles;
  const int nt = rest & 31;
  const size_t bz = rest >> 5;
  const int m0 = mt * 128;
  const int n0 = nt * 128;

  const f16* Bhb = Bh + bz * (size_t)N_PIX * K;
  const f16* Blb = Bl + bz * (size_t)N_PIX * K;
  OutT* Cb = C + bz * (size_t)M * N_PIX;

  f32x4 acc[4][4];
#pragma unroll
  for (int i = 0; i < 4; ++i)
#pragma unroll
    for (int j = 0; j < 4; ++j) acc[i][j] = (f32x4){0.f, 0.f, 0.f, 0.f};

  const int wm = w >> 1, wn = w & 1;
  const int fr = lane & 15;
  const int fk = (lane >> 4) * 8;

  const f16* gsrc[8];
  int sslot[8];
#pragma unroll
  for (int i = 0; i < 8; ++i) {
    const int s = w + i * 4;
    const int frag = s & 7;
    const f16* base;
    int row0;
    if (s < 8) {
      base = Ah; row0 = m0;
    } else if (s < 16) {
      base = Al; row0 = m0;
    } else if (s < 24) {
      base = Bhb; row0 = n0;
    } else {
      base = Blb; row0 = n0;
    }
    gsrc[i] = base + (size_t)(row0 + frag * 16 + fr) * K + fk;
    sslot[i] = s * 512;
  }

#pragma unroll
  for (int i = 0; i < 8; ++i)
    __builtin_amdgcn_global_load_lds(
        (const __attribute__((address_space(1))) unsigned int*)gsrc[i],
        (__attribute__((address_space(3))) unsigned int*)&sm[0][sslot[i]], 16, 0, 0);

  const int ntk = K / 32;
  int cur = 0;
  for (int tt = 0; tt < ntk; ++tt) {
    if (tt + 1 < ntk) {
#pragma unroll
      for (int i = 0; i < 8; ++i)
        __builtin_amdgcn_global_load_lds(
            (const __attribute__((address_space(1))) unsigned int*)(gsrc[i] + (tt + 1) * 32),
            (__attribute__((address_space(3))) unsigned int*)&sm[cur ^ 1][sslot[i]], 16, 0, 0);
      asm volatile("s_waitcnt vmcnt(8)" ::: "memory");
    } else {
      asm volatile("s_waitcnt vmcnt(0)" ::: "memory");
    }
    __builtin_amdgcn_s_barrier();
    const f16* smb = sm[cur];
    half8 ah[4], al[4], bh[4], bl[4];
#pragma unroll
    for (int mi = 0; mi < 4; ++mi) {
      ah[mi] = *(const half8*)&smb[(wm * 4 + mi) * 512 + lane * 8];
      al[mi] = *(const half8*)&smb[(8 + wm * 4 + mi) * 512 + lane * 8];
    }
#pragma unroll
    for (int ni = 0; ni < 4; ++ni) {
      bh[ni] = *(const half8*)&smb[(16 + wn * 4 + ni) * 512 + lane * 8];
      bl[ni] = *(const half8*)&smb[(24 + wn * 4 + ni) * 512 + lane * 8];
    }
#pragma unroll
    for (int mi = 0; mi < 4; ++mi)
#pragma unroll
      for (int ni = 0; ni < 4; ++ni) {
        acc[mi][ni] = __builtin_amdgcn_mfma_f32_16x16x32_f16(ah[mi], bh[ni], acc[mi][ni], 0, 0, 0);
        acc[mi][ni] = __builtin_amdgcn_mfma_f32_16x16x32_f16(ah[mi], bl[ni], acc[mi][ni], 0, 0, 0);
        acc[mi][ni] = __builtin_amdgcn_mfma_f32_16x16x32_f16(al[mi], bh[ni], acc[mi][ni], 0, 0, 0);
      }
    __builtin_amdgcn_s_barrier();
    cur ^= 1;
  }
  const int cr = (lane >> 4) * 4;
  const int cc = lane & 15;
#pragma unroll
  for (int mi = 0; mi < 4; ++mi)
#pragma unroll
    for (int ni = 0; ni < 4; ++ni) {
      OutT* p = Cb + (size_t)(m0 + wm * 64 + mi * 16 + cr) * N_PIX + n0 + wn * 64 + ni * 16 + cc;
#pragma unroll
      for (int r = 0; r < 4; ++r) p[(size_t)r * N_PIX] = (OutT)acc[mi][ni][r];
    }
}

// ---------------------------------------------------------------------------
// k_gemm1: C = A[M][K] * B[b][4096][K]^T, single-f16 MFMA (proj: no relu/div
// downstream -> f16 rounding adds only ~1e-4 abs). 16 slabs x 2 buf = 32 KB.
// ---------------------------------------------------------------------------
template <typename OutT>
__global__ __launch_bounds__(256) void k_gemm1(const f16* __restrict__ A,
                                               const f16* __restrict__ B,
                                               OutT* __restrict__ C,
                                               int M, int K) {
  __shared__ f16 sm[2][16 * 512];
  const int t = threadIdx.x;
  const int lane = t & 63;
  const int w = t >> 6;
  const int n0 = blockIdx.x * 128;
  const int m0 = blockIdx.y * 128;
  const size_t bz = blockIdx.z;
  const f16* Bb = B + bz * (size_t)N_PIX * K;
  OutT* Cb = C + bz * (size_t)M * N_PIX;

  f32x4 acc[4][4];
#pragma unroll
  for (int i = 0; i < 4; ++i)
#pragma unroll
    for (int j = 0; j < 4; ++j) acc[i][j] = (f32x4){0.f, 0.f, 0.f, 0.f};

  const int wm = w >> 1, wn = w & 1;
  const int fr = lane & 15;
  const int fk = (lane >> 4) * 8;

  const f16* gsrc[4];
  int sslot[4];
#pragma unroll
  for (int i = 0; i < 4; ++i) {
    const int s = w + i * 4;
    const int frag = s & 7;
    const f16* base;
    int row0;
    if (s < 8) {
      base = A; row0 = m0;
    } else {
      base = Bb; row0 = n0;
    }
    gsrc[i] = base + (size_t)(row0 + frag * 16 + fr) * K + fk;
    sslot[i] = s * 512;
  }

#pragma unroll
  for (int i = 0; i < 4; ++i)
    __builtin_amdgcn_global_load_lds(
        (const __attribute__((address_space(1))) unsigned int*)gsrc[i],
        (__attribute__((address_space(3))) unsigned int*)&sm[0][sslot[i]], 16, 0, 0);

  const int nt = K / 32;
  int cur = 0;
  for (int tt = 0; tt < nt; ++tt) {
    if (tt + 1 < nt) {
#pragma unroll
      for (int i = 0; i < 4; ++i)
        __builtin_amdgcn_global_load_lds(
            (const __attribute__((address_space(1))) unsigned int*)(gsrc[i] + (tt + 1) * 32),
            (__attribute__((address_space(3))) unsigned int*)&sm[cur ^ 1][sslot[i]], 16, 0, 0);
      asm volatile("s_waitcnt vmcnt(4)" ::: "memory");
    } else {
      asm volatile("s_waitcnt vmcnt(0)" ::: "memory");
    }
    __builtin_amdgcn_s_barrier();
    const f16* smb = sm[cur];
    half8 av[4], bv[4];
#pragma unroll
    for (int mi = 0; mi < 4; ++mi) av[mi] = *(const half8*)&smb[(wm * 4 + mi) * 512 + lane * 8];
#pragma unroll
    for (int ni = 0; ni < 4; ++ni) bv[ni] = *(const half8*)&smb[(8 + wn * 4 + ni) * 512 + lane * 8];
#pragma unroll
    for (int mi = 0; mi < 4; ++mi)
#pragma unroll
      for (int ni = 0; ni < 4; ++ni)
        acc[mi][ni] = __builtin_amdgcn_mfma_f32_16x16x32_f16(av[mi], bv[ni], acc[mi][ni], 0, 0, 0);
    __builtin_amdgcn_s_barrier();
    cur ^= 1;
  }
  const int cr = (lane >> 4) * 4;
  const int cc = lane & 15;
#pragma unroll
  for (int mi = 0; mi < 4; ++mi)
#pragma unroll
    for (int ni = 0; ni < 4; ++ni) {
      OutT* p = Cb + (size_t)(m0 + wm * 64 + mi * 16 + cr) * N_PIX + n0 + wn * 64 + ni * 16 + cc;
#pragma unroll
      for (int r = 0; r < 4; ++r) p[(size_t)r * N_PIX] = (OutT)acc[mi][ni][r];
    }
}

// ---------------------------------------------------------------------------
// k_dw: depthwise 5x5 (R8-proven split; fusion regressed twice — R3, R10).
// Block = (b, ch), full 64x64 plane, f32 LDS halo 19.6 KB -> 8 blocks/CU,
// thread = (col, 16-row strip), 5x5 register sliding window.
// ---------------------------------------------------------------------------
__global__ __launch_bounds__(256) void k_dw(const f16* __restrict__ qkv,
                                            const float* __restrict__ wdw,
                                            f16* __restrict__ dw) {
  __shared__ float sin_[68][72];
  const int t = threadIdx.x;
  const int bc = blockIdx.x;
  const int ch = bc % TD3;
  const f16* src = qkv + (size_t)bc * N_PIX;

  for (int i = t; i < 68 * 72 / 4; i += 256) ((f32x4*)sin_)[i] = (f32x4){0.f, 0.f, 0.f, 0.f};
  float wreg[25];
#pragma unroll
  for (int i = 0; i < 25; ++i) wreg[i] = wdw[(size_t)ch * 25 + i];
  __syncthreads();
  for (int i = t; i < 512; i += 256) {
    const int r = i >> 3, c8 = (i & 7) * 8;
    const half8 p = *(const half8*)(src + r * 64 + c8);
    f32x4 lo = {(float)p[0], (float)p[1], (float)p[2], (float)p[3]};
    f32x4 hi = {(float)p[4], (float)p[5], (float)p[6], (float)p[7]};
    *(f32x4*)&sin_[r + 2][c8 + 4] = lo;
    *(f32x4*)&sin_[r + 2][c8 + 8] = hi;
  }
  __syncthreads();

  const int c = t & 63;
  const int rg = t >> 6;
  const int r0 = rg * 16;
  float win[5][5];
#pragma unroll
  for (int r = 0; r < 4; ++r)
#pragma unroll
    for (int j = 0; j < 5; ++j) win[r][j] = sin_[r0 + r][c + 2 + j];
#pragma unroll
  for (int orow = 0; orow < 16; ++orow) {
    const int slot = (orow + 4) % 5;
#pragma unroll
    for (int j = 0; j < 5; ++j) win[slot][j] = sin_[r0 + orow + 4][c + 2 + j];
    float s = 0.f;
#pragma unroll
    for (int dr = 0; dr < 5; ++dr) {
      const int rs = (orow + dr) % 5;
#pragma unroll
      for (int dc = 0; dc < 5; ++dc) s = fmaf(win[rs][dc], wreg[dr * 5 + dc], s);
    }
    dw[(size_t)bc * N_PIX + (r0 + orow) * 64 + c] = (f16)s;
  }
}

// ---------------------------------------------------------------------------
// k_pw: grouped pointwise 8->8, streaming (dw buffer is L3-resident).
// ---------------------------------------------------------------------------
__global__ __launch_bounds__(256) void k_pw(const f16* __restrict__ dw,
                                            const float* __restrict__ wpw,
                                            f16* __restrict__ agg) {
  const int t = threadIdx.x;
  const int q = blockIdx.x;
  const int bg = blockIdx.y;
  const int g = bg % 96;
  float wp[64];
#pragma unroll
  for (int i = 0; i < 64; ++i) wp[i] = wpw[(size_t)g * 64 + i];
  const size_t base = ((size_t)(bg / 96) * TD3 + g * 8) * N_PIX + q * 1024;
  const int px0 = t * 4;
  float dv[8][4];
#pragma unroll
  for (int ic = 0; ic < 8; ++ic) {
    const f16x4 v = *(const f16x4*)(dw + base + (size_t)ic * N_PIX + px0);
#pragma unroll
    for (int j = 0; j < 4; ++j) dv[ic][j] = (float)v[j];
  }
#pragma unroll
  for (int oc = 0; oc < 8; ++oc) {
    f16x4 o;
#pragma unroll
    for (int j = 0; j < 4; ++j) {
      float s = 0.f;
#pragma unroll
      for (int ic = 0; ic < 8; ++ic) s = fmaf(dv[ic][j], wp[oc * 8 + ic], s);
      o[j] = (f16)s;
    }
    *(f16x4*)(agg + base + (size_t)oc * N_PIX + px0) = o;
  }
}

// ---------------------------------------------------------------------------
// k_kv: chunked kv partial sums (deterministic), f16 in, fp32 accumulate
// ---------------------------------------------------------------------------
__global__ __launch_bounds__(256) void k_kv(const f16* __restrict__ qkv,
                                            const f16* __restrict__ agg,
                                            float* __restrict__ kvbuf) {
  const int t = threadIdx.x;
  const int chunk = blockIdx.x;
  const int g = blockIdx.y;
  const int b = blockIdx.z;
  const f16* src = (g < 32) ? qkv : agg;
  const int base = (g & 31) * 24;
  const f16* kc = src + ((size_t)b * TD3 + base + 8) * N_PIX;
  const f16* vc = src + ((size_t)b * TD3 + base + 16) * N_PIX;

  float acc[72];
#pragma unroll
  for (int i = 0; i < 72; i++) acc[i] = 0.f;

  const int n0 = chunk * (N_PIX / KV_CHUNKS);
  for (int i = 0; i < (N_PIX / KV_CHUNKS) / 256; i++) {
    const int n = n0 + t + i * 256;
    float kd[8], ve[8];
#pragma unroll
    for (int d = 0; d < 8; d++) kd[d] = fmaxf((float)kc[(size_t)d * N_PIX + n], 0.f);
#pragma unroll
    for (int e = 0; e < 8; e++) ve[e] = (float)vc[(size_t)e * N_PIX + n];
#pragma unroll
    for (int d = 0; d < 8; d++) {
#pragma unroll
      for (int e = 0; e < 8; e++) acc[d * 9 + e] = fmaf(kd[d], ve[e], acc[d * 9 + e]);
      acc[d * 9 + 8] += kd[d];
    }
  }
#pragma unroll
  for (int i = 0; i < 72; i++) {
    float v = acc[i];
#pragma unroll
    for (int off = 32; off > 0; off >>= 1) v += __shfl_down(v, off, 64);
    acc[i] = v;
  }
  __shared__ float red[4][72];
  const int lane = t & 63, wv = t >> 6;
  if (lane == 0) {
#pragma unroll
    for (int i = 0; i < 72; i++) red[wv][i] = acc[i];
  }
  __syncthreads();
  if (t < 72) {
    const float s = red[0][t] + red[1][t] + red[2][t] + red[3][t];
    kvbuf[(((size_t)chunk * N_B + b) * N_G + g) * 72 + t] = s;
  }
}

// ---------------------------------------------------------------------------
// k_att: att^T[b][4096][512] f16; sums the kv chunk partials inline (same
// order as old k_kvsum -> bit-identical, one launch saved).
// ---------------------------------------------------------------------------
__global__ __launch_bounds__(256) void k_att(const f16* __restrict__ qkvh,
                                             const f16* __restrict__ aggh,
                                             const float* __restrict__ kvbuf,
                                             f16* __restrict__ atth) {
  __shared__ float skv[N_G * 72];
  __shared__ f16 sa[512][34];
  const int t = threadIdx.x;
  const int n0 = blockIdx.x * 32;
  const size_t b = blockIdx.y;
  for (int i = t; i < N_G * 72; i += 256) {
    float s = 0.f;
#pragma unroll
    for (int c = 0; c < KV_CHUNKS; c++)
      s += kvbuf[(size_t)c * (N_B * N_G * 72) + b * (N_G * 72) + i];
    skv[i] = s;
  }
  __syncthreads();
  const int px = t & 31, gq = t >> 5;
#pragma unroll
  for (int gi = 0; gi < 8; ++gi) {
    const int g = gq * 8 + gi;
    const f16* src = (g < 32) ? qkvh : aggh;
    const int base = (g & 31) * 24;
    const f16* qc = src + ((size_t)b * TD3 + base) * N_PIX + n0 + px;
    float num[8] = {0.f, 0.f, 0.f, 0.f, 0.f, 0.f, 0.f, 0.f};
    float den = 0.f;
#pragma unroll
    for (int d = 0; d < 8; ++d) {
      const float qd = fmaxf((float)qc[(size_t)d * N_PIX], 0.f);
      const float* kvg = &skv[g * 72 + d * 9];
#pragma unroll
      for (int e = 0; e < 8; ++e) num[e] = fmaf(qd, kvg[e], num[e]);
      den = fmaf(qd, kvg[8], den);
    }
    const float rd = 1.f / (den + 1e-15f);
#pragma unroll
    for (int e = 0; e < 8; ++e) sa[g * 8 + e][px] = (f16)(num[e] * rd);
  }
  __syncthreads();
  f16* dst = atth + (b * N_PIX + n0) * 512;
  for (int i = 0; i < 64; ++i) {
    const int idx = t + i * 256;
    dst[idx] = sa[idx & 511][idx >> 9];
  }
}

// ---------------------------------------------------------------------------
extern "C" void kernel_launch(void* const* d_in, const int* in_sizes, int n_in,
                              void* d_out, int out_size, void* d_ws, size_t ws_size,
                              hipStream_t stream) {
  const float* x = (const float*)d_in[0];
  const float* w_qkv = (const float*)d_in[1];
  const float* w_dw = (const float*)d_in[2];
  const float* w_pw = (const float*)d_in[3];
  const float* w_proj = (const float*)d_in[4];
  float* out = (float*)d_out;

  char* ws = (char*)d_ws;
  size_t off = 0;
  f16* qkvh = (f16*)(ws + off); off += (size_t)N_B * TD3 * N_PIX * 2;  // 50.3 MB
  f16* aggh = (f16*)(ws + off); off += (size_t)N_B * TD3 * N_PIX * 2;  // 50.3 MB
  float* kvbuf = (float*)(ws + off); off += (size_t)KV_CHUNKS * N_B * N_G * 72 * 4;
  f16* wqh = (f16*)(ws + off); off += (size_t)TD3 * C_IN * 2;
  f16* wql = (f16*)(ws + off); off += (size_t)TD3 * C_IN * 2;
  f16* wph = (f16*)(ws + off); off += (size_t)C_OUT * 512 * 2;
  // union region (disjoint lifetimes): xT(hi,lo) -> dwbuf -> attT(single)
  f16* xTh = (f16*)(ws + off);
  f16* xTl = xTh + (size_t)N_B * N_PIX * C_IN;
  f16* dwbuf = (f16*)(ws + off);
  f16* atth = (f16*)(ws + off);

  const int ncvt = (TD3 * C_IN + C_OUT * 512 + 255) / 256;
  k_cvtw<<<dim3(ncvt), 256, 0, stream>>>(w_qkv, w_proj, wqh, wql, wph);
  k_xT<<<dim3(N_PIX / 64, C_IN / 64, N_B), 256, 0, stream>>>(x, xTh, xTl);
  // grid: 6 m-tiles x 32 n-tiles x 8 batches = 1536 (XCD swizzle inside)
  k_gemm3<f16><<<dim3((TD3 / 128) * (N_PIX / 128) * N_B), 256, 0, stream>>>(
      wqh, wql, xTh, xTl, qkvh, TD3, C_IN);
  k_dw<<<dim3(N_B * TD3), 256, 0, stream>>>(qkvh, w_dw, dwbuf);
  k_pw<<<dim3(4, N_B * 96), 256, 0, stream>>>(dwbuf, w_pw, aggh);
  k_kv<<<dim3(KV_CHUNKS, N_G, N_B), 256, 0, stream>>>(qkvh, aggh, kvbuf);
  k_att<<<dim3(N_PIX / 32, N_B), 256, 0, stream>>>(qkvh, aggh, kvbuf, atth);
  k_gemm1<float><<<dim3(N_PIX / 128, C_OUT / 128, N_B), 256, 0, stream>>>(
      wph, atth, out, C_OUT, 512);
}

// Round 12
// 184.961 us; speedup vs baseline: 1.2955x; 1.0699x over previous
//
#include <hip/hip_runtime.h>

#define N_PIX 4096
#define IMG_W 64
#define C_IN 256
#define TD3 768
#define N_B 8
#define N_G 64
#define C_OUT 256
#define KV_CHUNKS 4

typedef _Float16 f16;
typedef _Float16 half8 __attribute__((ext_vector_type(8)));
typedef _Float16 f16x4 __attribute__((ext_vector_type(4)));
typedef float f32x4 __attribute__((ext_vector_type(4)));

// ---------------------------------------------------------------------------
// k_cvtw: convert + PERMUTE weights.
// w_qkv rows r: role j=r%24 (j<8 q, 8<=j<16 k, 16<=j<24 v), group g=r/24.
//   q rows  -> wqq_h/wqq_l [256][256] (hi/lo, qrow = g*8+j)
//   kv rows -> wqkv [512][256] (hi only — k/v tolerate 1-term, R12 analysis)
// w_proj -> single f16.
// ---------------------------------------------------------------------------
__global__ __launch_bounds__(256) void k_cvtw(const float* __restrict__ wq,
                                              const float* __restrict__ wp,
                                              f16* __restrict__ wqq_h,
                                              f16* __restrict__ wqq_l,
                                              f16* __restrict__ wqkv,
                                              f16* __restrict__ wph) {
  const int i = blockIdx.x * 256 + threadIdx.x;
  if (i < TD3 * C_IN) {
    const int r = i >> 8, k = i & 255;
    const float v = wq[i];
    const f16 h = (f16)v;
    const int g = r / 24, j = r % 24;
    if (j < 8) {
      const int qi = g * 8 + j;
      wqq_h[qi * 256 + k] = h;
      wqq_l[qi * 256 + k] = (f16)(v - (float)h);
    } else {
      const int kvi = g * 16 + (j - 8);
      wqkv[kvi * 256 + k] = h;
    }
  } else if (i < TD3 * C_IN + C_OUT * 512) {
    const int j = i - TD3 * C_IN;
    wph[j] = (f16)wp[j];
  }
}

// ---------------------------------------------------------------------------
// k_xT: x[b][256][4096] fp32 -> xT[b][4096][256] (hi,lo) f16.
// hi/lo REQUIRED for the q path (R6/R7 post-mortem: relu sign flips).
// ---------------------------------------------------------------------------
__global__ __launch_bounds__(256) void k_xT(const float* __restrict__ x,
                                            f16* __restrict__ xh,
                                            f16* __restrict__ xl) {
  __shared__ float st[64][65];
  const int t = threadIdx.x;
  const int n0 = blockIdx.x * 64;
  const int k0 = blockIdx.y * 64;
  const size_t b = blockIdx.z;
  const float* xb = x + b * (size_t)C_IN * N_PIX;
#pragma unroll
  for (int i = 0; i < 16; ++i) {
    const int idx = t + i * 256;
    const int r = idx >> 6, c = idx & 63;
    st[r][c] = xb[(size_t)(k0 + r) * N_PIX + n0 + c];
  }
  __syncthreads();
#pragma unroll
  for (int i = 0; i < 16; ++i) {
    const int idx = t + i * 256;
    const int n = idx >> 6, k = idx & 63;
    const float v = st[k][n];
    const f16 h = (f16)v;
    const size_t o = (b * N_PIX + n0 + n) * C_IN + k0 + k;
    xh[o] = h;
    xl[o] = (f16)(v - (float)h);
  }
}

// ---------------------------------------------------------------------------
// k_gemmq: qkv Q-rows = (Ah+Al)[256][256] * (Bh+Bl)^T, 3-term split-f16.
// R8-proven 128x128/BK=32 structure; M=256 -> 512 blocks = exactly 2/CU,
// single tail-free round. C-write scatters qrow -> channel (g*24+j).
// ---------------------------------------------------------------------------
__global__ __launch_bounds__(256) void k_gemmq(const f16* __restrict__ Ah,
                                               const f16* __restrict__ Al,
                                               const f16* __restrict__ Bh,
                                               const f16* __restrict__ Bl,
                                               f16* __restrict__ C,
                                               int M, int K) {
  __shared__ f16 sm[2][32 * 512];
  const int t = threadIdx.x;
  const int lane = t & 63;
  const int w = t >> 6;

  // bijective XCD swizzle (gridDim.x % 8 == 0), m-tile fastest
  const int per = gridDim.x >> 3;
  const int swz = (blockIdx.x & 7) * per + (blockIdx.x >> 3);
  const int mtiles = M >> 7;
  const int mt = swz % mtiles;
  const int rest = swz / mtiles;
  const int nt = rest & 31;
  const size_t bz = rest >> 5;
  const int m0 = mt * 128;
  const int n0 = nt * 128;

  const f16* Bhb = Bh + bz * (size_t)N_PIX * K;
  const f16* Blb = Bl + bz * (size_t)N_PIX * K;
  f16* Cb = C + bz * (size_t)TD3 * N_PIX;

  f32x4 acc[4][4];
#pragma unroll
  for (int i = 0; i < 4; ++i)
#pragma unroll
    for (int j = 0; j < 4; ++j) acc[i][j] = (f32x4){0.f, 0.f, 0.f, 0.f};

  const int wm = w >> 1, wn = w & 1;
  const int fr = lane & 15;
  const int fk = (lane >> 4) * 8;

  const f16* gsrc[8];
  int sslot[8];
#pragma unroll
  for (int i = 0; i < 8; ++i) {
    const int s = w + i * 4;
    const int frag = s & 7;
    const f16* base;
    int row0;
    if (s < 8) {
      base = Ah; row0 = m0;
    } else if (s < 16) {
      base = Al; row0 = m0;
    } else if (s < 24) {
      base = Bhb; row0 = n0;
    } else {
      base = Blb; row0 = n0;
    }
    gsrc[i] = base + (size_t)(row0 + frag * 16 + fr) * K + fk;
    sslot[i] = s * 512;
  }

#pragma unroll
  for (int i = 0; i < 8; ++i)
    __builtin_amdgcn_global_load_lds(
        (const __attribute__((address_space(1))) unsigned int*)gsrc[i],
        (__attribute__((address_space(3))) unsigned int*)&sm[0][sslot[i]], 16, 0, 0);

  const int ntk = K / 32;
  int cur = 0;
  for (int tt = 0; tt < ntk; ++tt) {
    if (tt + 1 < ntk) {
#pragma unroll
      for (int i = 0; i < 8; ++i)
        __builtin_amdgcn_global_load_lds(
            (const __attribute__((address_space(1))) unsigned int*)(gsrc[i] + (tt + 1) * 32),
            (__attribute__((address_space(3))) unsigned int*)&sm[cur ^ 1][sslot[i]], 16, 0, 0);
      asm volatile("s_waitcnt vmcnt(8)" ::: "memory");
    } else {
      asm volatile("s_waitcnt vmcnt(0)" ::: "memory");
    }
    __builtin_amdgcn_s_barrier();
    const f16* smb = sm[cur];
    half8 ah[4], al[4], bh[4], bl[4];
#pragma unroll
    for (int mi = 0; mi < 4; ++mi) {
      ah[mi] = *(const half8*)&smb[(wm * 4 + mi) * 512 + lane * 8];
      al[mi] = *(const half8*)&smb[(8 + wm * 4 + mi) * 512 + lane * 8];
    }
#pragma unroll
    for (int ni = 0; ni < 4; ++ni) {
      bh[ni] = *(const half8*)&smb[(16 + wn * 4 + ni) * 512 + lane * 8];
      bl[ni] = *(const half8*)&smb[(24 + wn * 4 + ni) * 512 + lane * 8];
    }
#pragma unroll
    for (int mi = 0; mi < 4; ++mi)
#pragma unroll
      for (int ni = 0; ni < 4; ++ni) {
        acc[mi][ni] = __builtin_amdgcn_mfma_f32_16x16x32_f16(ah[mi], bh[ni], acc[mi][ni], 0, 0, 0);
        acc[mi][ni] = __builtin_amdgcn_mfma_f32_16x16x32_f16(ah[mi], bl[ni], acc[mi][ni], 0, 0, 0);
        acc[mi][ni] = __builtin_amdgcn_mfma_f32_16x16x32_f16(al[mi], bh[ni], acc[mi][ni], 0, 0, 0);
      }
    __builtin_amdgcn_s_barrier();
    cur ^= 1;
  }
  const int cr = (lane >> 4) * 4;
  const int cc = lane & 15;
#pragma unroll
  for (int mi = 0; mi < 4; ++mi)
#pragma unroll
    for (int ni = 0; ni < 4; ++ni) {
#pragma unroll
      for (int r = 0; r < 4; ++r) {
        const int row = m0 + wm * 64 + mi * 16 + cr + r;      // qrow in [0,256)
        const int ch = (row >> 3) * 24 + (row & 7);           // -> channel
        Cb[(size_t)ch * N_PIX + n0 + wn * 64 + ni * 16 + cc] = (f16)acc[mi][ni][r];
      }
    }
}

// ---------------------------------------------------------------------------
// k_gemmkv: qkv K/V-rows = A[512][256] * Bh^T, 1-term f16, BK=64.
// k/v tolerate 1-term: errors (~4e-4 abs) pass through 1-Lipschitz relu into
// 4096-term kv sums (no divide-amplification — that is q-only).
// 128x128 tile, BK=64: 16 slabs x 2KB x 2 buf = 64 KB; 4 iters of 32 MFMA.
// C-write scatters kvrow -> channel (g*24+8+j).
// ---------------------------------------------------------------------------
__global__ __launch_bounds__(256) void k_gemmkv(const f16* __restrict__ A,
                                                const f16* __restrict__ B,
                                                f16* __restrict__ C,
                                                int M, int K) {
  __shared__ f16 sm[2][16 * 1024];
  const int t = threadIdx.x;
  const int lane = t & 63;
  const int w = t >> 6;

  const int per = gridDim.x >> 3;
  const int swz = (blockIdx.x & 7) * per + (blockIdx.x >> 3);
  const int mtiles = M >> 7;  // 4
  const int mt = swz % mtiles;
  const int rest = swz / mtiles;
  const int nt = rest & 31;
  const size_t bz = rest >> 5;
  const int m0 = mt * 128;
  const int n0 = nt * 128;

  const f16* Bb = B + bz * (size_t)N_PIX * K;
  f16* Cb = C + bz * (size_t)TD3 * N_PIX;

  f32x4 acc[4][4];
#pragma unroll
  for (int i = 0; i < 4; ++i)
#pragma unroll
    for (int j = 0; j < 4; ++j) acc[i][j] = (f32x4){0.f, 0.f, 0.f, 0.f};

  const int wm = w >> 1, wn = w & 1;
  // staging: slab s = w + i*4 (s<8: A frag s; else B frag s-8), 2 loads/slab.
  // slab layout row-major [16 rows][64 k] f16 (2KB). load j covers rows j*8..j*8+7:
  //   lane l -> row j*8 + l/8, k-octet (l%8)*8; LDS byte = s*2048 + j*1024 + l*16.
  const int fr2 = lane >> 3;
  const int fko = (lane & 7) * 8;
  const f16* gsrc[4][2];
  int sslot[4][2];
#pragma unroll
  for (int i = 0; i < 4; ++i) {
    const int s = w + i * 4;
    const int frag = s & 7;
    const f16* base = (s < 8) ? A : Bb;
    const int row0 = (s < 8) ? m0 : n0;
#pragma unroll
    for (int j = 0; j < 2; ++j) {
      gsrc[i][j] = base + (size_t)(row0 + frag * 16 + j * 8 + fr2) * K + fko;
      sslot[i][j] = s * 1024 + j * 512;  // f16 elements
    }
  }

#pragma unroll
  for (int i = 0; i < 4; ++i)
#pragma unroll
    for (int j = 0; j < 2; ++j)
      __builtin_amdgcn_global_load_lds(
          (const __attribute__((address_space(1))) unsigned int*)gsrc[i][j],
          (__attribute__((address_space(3))) unsigned int*)&sm[0][sslot[i][j]], 16, 0, 0);

  const int ntk = K / 64;  // 4
  int cur = 0;
  for (int tt = 0; tt < ntk; ++tt) {
    if (tt + 1 < ntk) {
#pragma unroll
      for (int i = 0; i < 4; ++i)
#pragma unroll
        for (int j = 0; j < 2; ++j)
          __builtin_amdgcn_global_load_lds(
              (const __attribute__((address_space(1))) unsigned int*)(gsrc[i][j] + (tt + 1) * 64),
              (__attribute__((address_space(3))) unsigned int*)&sm[cur ^ 1][sslot[i][j]], 16, 0, 0);
      asm volatile("s_waitcnt vmcnt(8)" ::: "memory");
    } else {
      asm volatile("s_waitcnt vmcnt(0)" ::: "memory");
    }
    __builtin_amdgcn_s_barrier();
    const f16* smb = sm[cur];
    // fragment read: elem = slab*1024 + (lane&15)*64 + (lane>>4)*8 + kk*32
    const int fb = (lane & 15) * 64 + (lane >> 4) * 8;
    half8 av[4][2], bv[4][2];
#pragma unroll
    for (int mi = 0; mi < 4; ++mi)
#pragma unroll
      for (int kk = 0; kk < 2; ++kk)
        av[mi][kk] = *(const half8*)&smb[(wm * 4 + mi) * 1024 + fb + kk * 32];
#pragma unroll
    for (int ni = 0; ni < 4; ++ni)
#pragma unroll
      for (int kk = 0; kk < 2; ++kk)
        bv[ni][kk] = *(const half8*)&smb[(8 + wn * 4 + ni) * 1024 + fb + kk * 32];
#pragma unroll
    for (int kk = 0; kk < 2; ++kk)
#pragma unroll
      for (int mi = 0; mi < 4; ++mi)
#pragma unroll
        for (int ni = 0; ni < 4; ++ni)
          acc[mi][ni] = __builtin_amdgcn_mfma_f32_16x16x32_f16(av[mi][kk], bv[ni][kk], acc[mi][ni], 0, 0, 0);
    __builtin_amdgcn_s_barrier();
    cur ^= 1;
  }
  const int cr = (lane >> 4) * 4;
  const int cc = lane & 15;
#pragma unroll
  for (int mi = 0; mi < 4; ++mi)
#pragma unroll
    for (int ni = 0; ni < 4; ++ni) {
#pragma unroll
      for (int r = 0; r < 4; ++r) {
        const int row = m0 + wm * 64 + mi * 16 + cr + r;      // kvrow in [0,512)
        const int ch = (row >> 4) * 24 + 8 + (row & 15);      // -> channel
        Cb[(size_t)ch * N_PIX + n0 + wn * 64 + ni * 16 + cc] = (f16)acc[mi][ni][r];
      }
    }
}

// ---------------------------------------------------------------------------
// k_gemm1: C = A[M][K] * B[b][4096][K]^T, single-f16 MFMA (proj).
// ---------------------------------------------------------------------------
template <typename OutT>
__global__ __launch_bounds__(256) void k_gemm1(const f16* __restrict__ A,
                                               const f16* __restrict__ B,
                                               OutT* __restrict__ C,
                                               int M, int K) {
  __shared__ f16 sm[2][16 * 512];
  const int t = threadIdx.x;
  const int lane = t & 63;
  const int w = t >> 6;
  const int n0 = blockIdx.x * 128;
  const int m0 = blockIdx.y * 128;
  const size_t bz = blockIdx.z;
  const f16* Bb = B + bz * (size_t)N_PIX * K;
  OutT* Cb = C + bz * (size_t)M * N_PIX;

  f32x4 acc[4][4];
#pragma unroll
  for (int i = 0; i < 4; ++i)
#pragma unroll
    for (int j = 0; j < 4; ++j) acc[i][j] = (f32x4){0.f, 0.f, 0.f, 0.f};

  const int wm = w >> 1, wn = w & 1;
  const int fr = lane & 15;
  const int fk = (lane >> 4) * 8;

  const f16* gsrc[4];
  int sslot[4];
#pragma unroll
  for (int i = 0; i < 4; ++i) {
    const int s = w + i * 4;
    const int frag = s & 7;
    const f16* base;
    int row0;
    if (s < 8) {
      base = A; row0 = m0;
    } else {
      base = Bb; row0 = n0;
    }
    gsrc[i] = base + (size_t)(row0 + frag * 16 + fr) * K + fk;
    sslot[i] = s * 512;
  }

#pragma unroll
  for (int i = 0; i < 4; ++i)
    __builtin_amdgcn_global_load_lds(
        (const __attribute__((address_space(1))) unsigned int*)gsrc[i],
        (__attribute__((address_space(3))) unsigned int*)&sm[0][sslot[i]], 16, 0, 0);

  const int nt = K / 32;
  int cur = 0;
  for (int tt = 0; tt < nt; ++tt) {
    if (tt + 1 < nt) {
#pragma unroll
      for (int i = 0; i < 4; ++i)
        __builtin_amdgcn_global_load_lds(
            (const __attribute__((address_space(1))) unsigned int*)(gsrc[i] + (tt + 1) * 32),
            (__attribute__((address_space(3))) unsigned int*)&sm[cur ^ 1][sslot[i]], 16, 0, 0);
      asm volatile("s_waitcnt vmcnt(4)" ::: "memory");
    } else {
      asm volatile("s_waitcnt vmcnt(0)" ::: "memory");
    }
    __builtin_amdgcn_s_barrier();
    const f16* smb = sm[cur];
    half8 av[4], bv[4];
#pragma unroll
    for (int mi = 0; mi < 4; ++mi) av[mi] = *(const half8*)&smb[(wm * 4 + mi) * 512 + lane * 8];
#pragma unroll
    for (int ni = 0; ni < 4; ++ni) bv[ni] = *(const half8*)&smb[(8 + wn * 4 + ni) * 512 + lane * 8];
#pragma unroll
    for (int mi = 0; mi < 4; ++mi)
#pragma unroll
      for (int ni = 0; ni < 4; ++ni)
        acc[mi][ni] = __builtin_amdgcn_mfma_f32_16x16x32_f16(av[mi], bv[ni], acc[mi][ni], 0, 0, 0);
    __builtin_amdgcn_s_barrier();
    cur ^= 1;
  }
  const int cr = (lane >> 4) * 4;
  const int cc = lane & 15;
#pragma unroll
  for (int mi = 0; mi < 4; ++mi)
#pragma unroll
    for (int ni = 0; ni < 4; ++ni) {
      OutT* p = Cb + (size_t)(m0 + wm * 64 + mi * 16 + cr) * N_PIX + n0 + wn * 64 + ni * 16 + cc;
#pragma unroll
      for (int r = 0; r < 4; ++r) p[(size_t)r * N_PIX] = (OutT)acc[mi][ni][r];
    }
}

// ---------------------------------------------------------------------------
// k_dw: depthwise 5x5 (split form — fusion regressed twice: R3, R10).
// ---------------------------------------------------------------------------
__global__ __launch_bounds__(256) void k_dw(const f16* __restrict__ qkv,
                                            const float* __restrict__ wdw,
                                            f16* __restrict__ dw) {
  __shared__ float sin_[68][72];
  const int t = threadIdx.x;
  const int bc = blockIdx.x;
  const int ch = bc % TD3;
  const f16* src = qkv + (size_t)bc * N_PIX;

  for (int i = t; i < 68 * 72 / 4; i += 256) ((f32x4*)sin_)[i] = (f32x4){0.f, 0.f, 0.f, 0.f};
  float wreg[25];
#pragma unroll
  for (int i = 0; i < 25; ++i) wreg[i] = wdw[(size_t)ch * 25 + i];
  __syncthreads();
  for (int i = t; i < 512; i += 256) {
    const int r = i >> 3, c8 = (i & 7) * 8;
    const half8 p = *(const half8*)(src + r * 64 + c8);
    f32x4 lo = {(float)p[0], (float)p[1], (float)p[2], (float)p[3]};
    f32x4 hi = {(float)p[4], (float)p[5], (float)p[6], (float)p[7]};
    *(f32x4*)&sin_[r + 2][c8 + 4] = lo;
    *(f32x4*)&sin_[r + 2][c8 + 8] = hi;
  }
  __syncthreads();

  const int c = t & 63;
  const int rg = t >> 6;
  const int r0 = rg * 16;
  float win[5][5];
#pragma unroll
  for (int r = 0; r < 4; ++r)
#pragma unroll
    for (int j = 0; j < 5; ++j) win[r][j] = sin_[r0 + r][c + 2 + j];
#pragma unroll
  for (int orow = 0; orow < 16; ++orow) {
    const int slot = (orow + 4) % 5;
#pragma unroll
    for (int j = 0; j < 5; ++j) win[slot][j] = sin_[r0 + orow + 4][c + 2 + j];
    float s = 0.f;
#pragma unroll
    for (int dr = 0; dr < 5; ++dr) {
      const int rs = (orow + dr) % 5;
#pragma unroll
      for (int dc = 0; dc < 5; ++dc) s = fmaf(win[rs][dc], wreg[dr * 5 + dc], s);
    }
    dw[(size_t)bc * N_PIX + (r0 + orow) * 64 + c] = (f16)s;
  }
}

// ---------------------------------------------------------------------------
// k_pw: grouped pointwise 8->8, streaming.
// ---------------------------------------------------------------------------
__global__ __launch_bounds__(256) void k_pw(const f16* __restrict__ dw,
                                            const float* __restrict__ wpw,
                                            f16* __restrict__ agg) {
  const int t = threadIdx.x;
  const int q = blockIdx.x;
  const int bg = blockIdx.y;
  const int g = bg % 96;
  float wp[64];
#pragma unroll
  for (int i = 0; i < 64; ++i) wp[i] = wpw[(size_t)g * 64 + i];
  const size_t base = ((size_t)(bg / 96) * TD3 + g * 8) * N_PIX + q * 1024;
  const int px0 = t * 4;
  float dv[8][4];
#pragma unroll
  for (int ic = 0; ic < 8; ++ic) {
    const f16x4 v = *(const f16x4*)(dw + base + (size_t)ic * N_PIX + px0);
#pragma unroll
    for (int j = 0; j < 4; ++j) dv[ic][j] = (float)v[j];
  }
#pragma unroll
  for (int oc = 0; oc < 8; ++oc) {
    f16x4 o;
#pragma unroll
    for (int j = 0; j < 4; ++j) {
      float s = 0.f;
#pragma unroll
      for (int ic = 0; ic < 8; ++ic) s = fmaf(dv[ic][j], wp[oc * 8 + ic], s);
      o[j] = (f16)s;
    }
    *(f16x4*)(agg + base + (size_t)oc * N_PIX + px0) = o;
  }
}

// ---------------------------------------------------------------------------
// k_kv: chunked kv partial sums (deterministic), f16 in, fp32 accumulate
// ---------------------------------------------------------------------------
__global__ __launch_bounds__(256) void k_kv(const f16* __restrict__ qkv,
                                            const f16* __restrict__ agg,
                                            float* __restrict__ kvbuf) {
  const int t = threadIdx.x;
  const int chunk = blockIdx.x;
  const int g = blockIdx.y;
  const int b = blockIdx.z;
  const f16* src = (g < 32) ? qkv : agg;
  const int base = (g & 31) * 24;
  const f16* kc = src + ((size_t)b * TD3 + base + 8) * N_PIX;
  const f16* vc = src + ((size_t)b * TD3 + base + 16) * N_PIX;

  float acc[72];
#pragma unroll
  for (int i = 0; i < 72; i++) acc[i] = 0.f;

  const int n0 = chunk * (N_PIX / KV_CHUNKS);
  for (int i = 0; i < (N_PIX / KV_CHUNKS) / 256; i++) {
    const int n = n0 + t + i * 256;
    float kd[8], ve[8];
#pragma unroll
    for (int d = 0; d < 8; d++) kd[d] = fmaxf((float)kc[(size_t)d * N_PIX + n], 0.f);
#pragma unroll
    for (int e = 0; e < 8; e++) ve[e] = (float)vc[(size_t)e * N_PIX + n];
#pragma unroll
    for (int d = 0; d < 8; d++) {
#pragma unroll
      for (int e = 0; e < 8; e++) acc[d * 9 + e] = fmaf(kd[d], ve[e], acc[d * 9 + e]);
      acc[d * 9 + 8] += kd[d];
    }
  }
#pragma unroll
  for (int i = 0; i < 72; i++) {
    float v = acc[i];
#pragma unroll
    for (int off = 32; off > 0; off >>= 1) v += __shfl_down(v, off, 64);
    acc[i] = v;
  }
  __shared__ float red[4][72];
  const int lane = t & 63, wv = t >> 6;
  if (lane == 0) {
#pragma unroll
    for (int i = 0; i < 72; i++) red[wv][i] = acc[i];
  }
  __syncthreads();
  if (t < 72) {
    const float s = red[0][t] + red[1][t] + red[2][t] + red[3][t];
    kvbuf[(((size_t)chunk * N_B + b) * N_G + g) * 72 + t] = s;
  }
}

// ---------------------------------------------------------------------------
// k_att: att^T[b][4096][512] f16; sums kv chunk partials inline.
// ---------------------------------------------------------------------------
__global__ __launch_bounds__(256) void k_att(const f16* __restrict__ qkvh,
                                             const f16* __restrict__ aggh,
                                             const float* __restrict__ kvbuf,
                                             f16* __restrict__ atth) {
  __shared__ float skv[N_G * 72];
  __shared__ f16 sa[512][34];
  const int t = threadIdx.x;
  const int n0 = blockIdx.x * 32;
  const size_t b = blockIdx.y;
  for (int i = t; i < N_G * 72; i += 256) {
    float s = 0.f;
#pragma unroll
    for (int c = 0; c < KV_CHUNKS; c++)
      s += kvbuf[(size_t)c * (N_B * N_G * 72) + b * (N_G * 72) + i];
    skv[i] = s;
  }
  __syncthreads();
  const int px = t & 31, gq = t >> 5;
#pragma unroll
  for (int gi = 0; gi < 8; ++gi) {
    const int g = gq * 8 + gi;
    const f16* src = (g < 32) ? qkvh : aggh;
    const int base = (g & 31) * 24;
    const f16* qc = src + ((size_t)b * TD3 + base) * N_PIX + n0 + px;
    float num[8] = {0.f, 0.f, 0.f, 0.f, 0.f, 0.f, 0.f, 0.f};
    float den = 0.f;
#pragma unroll
    for (int d = 0; d < 8; ++d) {
      const float qd = fmaxf((float)qc[(size_t)d * N_PIX], 0.f);
      const float* kvg = &skv[g * 72 + d * 9];
#pragma unroll
      for (int e = 0; e < 8; ++e) num[e] = fmaf(qd, kvg[e], num[e]);
      den = fmaf(qd, kvg[8], den);
    }
    const float rd = 1.f / (den + 1e-15f);
#pragma unroll
    for (int e = 0; e < 8; ++e) sa[g * 8 + e][px] = (f16)(num[e] * rd);
  }
  __syncthreads();
  f16* dst = atth + (b * N_PIX + n0) * 512;
  for (int i = 0; i < 64; ++i) {
    const int idx = t + i * 256;
    dst[idx] = sa[idx & 511][idx >> 9];
  }
}

// ---------------------------------------------------------------------------
extern "C" void kernel_launch(void* const* d_in, const int* in_sizes, int n_in,
                              void* d_out, int out_size, void* d_ws, size_t ws_size,
                              hipStream_t stream) {
  const float* x = (const float*)d_in[0];
  const float* w_qkv = (const float*)d_in[1];
  const float* w_dw = (const float*)d_in[2];
  const float* w_pw = (const float*)d_in[3];
  const float* w_proj = (const float*)d_in[4];
  float* out = (float*)d_out;

  char* ws = (char*)d_ws;
  size_t off = 0;
  f16* qkvh = (f16*)(ws + off); off += (size_t)N_B * TD3 * N_PIX * 2;  // 50.3 MB
  f16* aggh = (f16*)(ws + off); off += (size_t)N_B * TD3 * N_PIX * 2;  // 50.3 MB
  float* kvbuf = (float*)(ws + off); off += (size_t)KV_CHUNKS * N_B * N_G * 72 * 4;
  f16* wqq_h = (f16*)(ws + off); off += (size_t)256 * C_IN * 2;
  f16* wqq_l = (f16*)(ws + off); off += (size_t)256 * C_IN * 2;
  f16* wqkv = (f16*)(ws + off); off += (size_t)512 * C_IN * 2;
  f16* wph = (f16*)(ws + off); off += (size_t)C_OUT * 512 * 2;
  // union region (disjoint lifetimes): xT(hi,lo) -> dwbuf -> attT(single)
  f16* xTh = (f16*)(ws + off);
  f16* xTl = xTh + (size_t)N_B * N_PIX * C_IN;
  f16* dwbuf = (f16*)(ws + off);
  f16* atth = (f16*)(ws + off);

  const int ncvt = (TD3 * C_IN + C_OUT * 512 + 255) / 256;
  k_cvtw<<<dim3(ncvt), 256, 0, stream>>>(w_qkv, w_proj, wqq_h, wqq_l, wqkv, wph);
  k_xT<<<dim3(N_PIX / 64, C_IN / 64, N_B), 256, 0, stream>>>(x, xTh, xTl);
  // q rows: 2 m-tiles x 32 nt x 8 b = 512 blocks (exactly 2/CU, one round)
  k_gemmq<<<dim3(2 * 32 * N_B), 256, 0, stream>>>(
      wqq_h, wqq_l, xTh, xTl, qkvh, 256, C_IN);
  // kv rows: 4 m-tiles x 32 nt x 8 b = 1024 blocks, BK=64, 1-term
  k_gemmkv<<<dim3(4 * 32 * N_B), 256, 0, stream>>>(
      wqkv, xTh, qkvh, 512, C_IN);
  k_dw<<<dim3(N_B * TD3), 256, 0, stream>>>(qkvh, w_dw, dwbuf);
  k_pw<<<dim3(4, N_B * 96), 256, 0, stream>>>(dwbuf, w_pw, aggh);
  k_kv<<<dim3(KV_CHUNKS, N_G, N_B), 256, 0, stream>>>(qkvh, aggh, kvbuf);
  k_att<<<dim3(N_PIX / 32, N_B), 256, 0, stream>>>(qkvh, aggh, kvbuf, atth);
  k_gemm1<float><<<dim3(N_PIX / 128, C_OUT / 128, N_B), 256, 0, stream>>>(
      wph, atth, out, C_OUT, 512);
}

// Round 13
// 158.242 us; speedup vs baseline: 1.5143x; 1.1688x over previous
//
#include <hip/hip_runtime.h>

#define N_PIX 4096
#define IMG_W 64
#define C_IN 256
#define TD3 768
#define N_B 8
#define N_G 64
#define C_OUT 256

typedef _Float16 f16;
typedef _Float16 half8 __attribute__((ext_vector_type(8)));
typedef _Float16 f16x4 __attribute__((ext_vector_type(4)));
typedef float f32x4 __attribute__((ext_vector_type(4)));

// ---------------------------------------------------------------------------
// k_cvtw: convert + PERMUTE weights.
// w_qkv rows r: role j=r%24 (j<8 q, 8<=j<16 k, 16<=j<24 v), group g=r/24.
//   q rows  -> wqq_h/wqq_l [256][256] (hi/lo); kv rows -> wqkv [512][256] hi.
// w_proj -> single f16.
// ---------------------------------------------------------------------------
__global__ __launch_bounds__(256) void k_cvtw(const float* __restrict__ wq,
                                              const float* __restrict__ wp,
                                              f16* __restrict__ wqq_h,
                                              f16* __restrict__ wqq_l,
                                              f16* __restrict__ wqkv,
                                              f16* __restrict__ wph) {
  const int i = blockIdx.x * 256 + threadIdx.x;
  if (i < TD3 * C_IN) {
    const int r = i >> 8, k = i & 255;
    const float v = wq[i];
    const f16 h = (f16)v;
    const int g = r / 24, j = r % 24;
    if (j < 8) {
      const int qi = g * 8 + j;
      wqq_h[qi * 256 + k] = h;
      wqq_l[qi * 256 + k] = (f16)(v - (float)h);
    } else {
      const int kvi = g * 16 + (j - 8);
      wqkv[kvi * 256 + k] = h;
    }
  } else if (i < TD3 * C_IN + C_OUT * 512) {
    const int j = i - TD3 * C_IN;
    wph[j] = (f16)wp[j];
  }
}

// ---------------------------------------------------------------------------
// k_xT: x[b][256][4096] fp32 -> xT[b][4096][256] (hi,lo) f16.
// hi/lo REQUIRED for the q path (R6/R7 post-mortem: relu sign flips).
// ---------------------------------------------------------------------------
__global__ __launch_bounds__(256) void k_xT(const float* __restrict__ x,
                                            f16* __restrict__ xh,
                                            f16* __restrict__ xl) {
  __shared__ float st[64][65];
  const int t = threadIdx.x;
  const int n0 = blockIdx.x * 64;
  const int k0 = blockIdx.y * 64;
  const size_t b = blockIdx.z;
  const float* xb = x + b * (size_t)C_IN * N_PIX;
#pragma unroll
  for (int i = 0; i < 16; ++i) {
    const int idx = t + i * 256;
    const int r = idx >> 6, c = idx & 63;
    st[r][c] = xb[(size_t)(k0 + r) * N_PIX + n0 + c];
  }
  __syncthreads();
#pragma unroll
  for (int i = 0; i < 16; ++i) {
    const int idx = t + i * 256;
    const int n = idx >> 6, k = idx & 63;
    const float v = st[k][n];
    const f16 h = (f16)v;
    const size_t o = (b * N_PIX + n0 + n) * C_IN + k0 + k;
    xh[o] = h;
    xl[o] = (f16)(v - (float)h);
  }
}

// ---------------------------------------------------------------------------
// k_gemmq: qkv Q-rows = (Ah+Al)[256][256] * (Bh+Bl)^T, 3-term split-f16.
// R8-proven 128x128/BK=32 structure; 512 blocks = exactly 2/CU.
// C-write scatters qrow -> channel (g*24+j).
// ---------------------------------------------------------------------------
__global__ __launch_bounds__(256) void k_gemmq(const f16* __restrict__ Ah,
                                               const f16* __restrict__ Al,
                                               const f16* __restrict__ Bh,
                                               const f16* __restrict__ Bl,
                                               f16* __restrict__ C,
                                               int M, int K) {
  __shared__ f16 sm[2][32 * 512];
  const int t = threadIdx.x;
  const int lane = t & 63;
  const int w = t >> 6;

  const int per = gridDim.x >> 3;
  const int swz = (blockIdx.x & 7) * per + (blockIdx.x >> 3);
  const int mtiles = M >> 7;
  const int mt = swz % mtiles;
  const int rest = swz / mtiles;
  const int nt = rest & 31;
  const size_t bz = rest >> 5;
  const int m0 = mt * 128;
  const int n0 = nt * 128;

  const f16* Bhb = Bh + bz * (size_t)N_PIX * K;
  const f16* Blb = Bl + bz * (size_t)N_PIX * K;
  f16* Cb = C + bz * (size_t)TD3 * N_PIX;

  f32x4 acc[4][4];
#pragma unroll
  for (int i = 0; i < 4; ++i)
#pragma unroll
    for (int j = 0; j < 4; ++j) acc[i][j] = (f32x4){0.f, 0.f, 0.f, 0.f};

  const int wm = w >> 1, wn = w & 1;
  const int fr = lane & 15;
  const int fk = (lane >> 4) * 8;

  const f16* gsrc[8];
  int sslot[8];
#pragma unroll
  for (int i = 0; i < 8; ++i) {
    const int s = w + i * 4;
    const int frag = s & 7;
    const f16* base;
    int row0;
    if (s < 8) {
      base = Ah; row0 = m0;
    } else if (s < 16) {
      base = Al; row0 = m0;
    } else if (s < 24) {
      base = Bhb; row0 = n0;
    } else {
      base = Blb; row0 = n0;
    }
    gsrc[i] = base + (size_t)(row0 + frag * 16 + fr) * K + fk;
    sslot[i] = s * 512;
  }

#pragma unroll
  for (int i = 0; i < 8; ++i)
    __builtin_amdgcn_global_load_lds(
        (const __attribute__((address_space(1))) unsigned int*)gsrc[i],
        (__attribute__((address_space(3))) unsigned int*)&sm[0][sslot[i]], 16, 0, 0);

  const int ntk = K / 32;
  int cur = 0;
  for (int tt = 0; tt < ntk; ++tt) {
    if (tt + 1 < ntk) {
#pragma unroll
      for (int i = 0; i < 8; ++i)
        __builtin_amdgcn_global_load_lds(
            (const __attribute__((address_space(1))) unsigned int*)(gsrc[i] + (tt + 1) * 32),
            (__attribute__((address_space(3))) unsigned int*)&sm[cur ^ 1][sslot[i]], 16, 0, 0);
      asm volatile("s_waitcnt vmcnt(8)" ::: "memory");
    } else {
      asm volatile("s_waitcnt vmcnt(0)" ::: "memory");
    }
    __builtin_amdgcn_s_barrier();
    const f16* smb = sm[cur];
    half8 ah[4], al[4], bh[4], bl[4];
#pragma unroll
    for (int mi = 0; mi < 4; ++mi) {
      ah[mi] = *(const half8*)&smb[(wm * 4 + mi) * 512 + lane * 8];
      al[mi] = *(const half8*)&smb[(8 + wm * 4 + mi) * 512 + lane * 8];
    }
#pragma unroll
    for (int ni = 0; ni < 4; ++ni) {
      bh[ni] = *(const half8*)&smb[(16 + wn * 4 + ni) * 512 + lane * 8];
      bl[ni] = *(const half8*)&smb[(24 + wn * 4 + ni) * 512 + lane * 8];
    }
#pragma unroll
    for (int mi = 0; mi < 4; ++mi)
#pragma unroll
      for (int ni = 0; ni < 4; ++ni) {
        acc[mi][ni] = __builtin_amdgcn_mfma_f32_16x16x32_f16(ah[mi], bh[ni], acc[mi][ni], 0, 0, 0);
        acc[mi][ni] = __builtin_amdgcn_mfma_f32_16x16x32_f16(ah[mi], bl[ni], acc[mi][ni], 0, 0, 0);
        acc[mi][ni] = __builtin_amdgcn_mfma_f32_16x16x32_f16(al[mi], bh[ni], acc[mi][ni], 0, 0, 0);
      }
    __builtin_amdgcn_s_barrier();
    cur ^= 1;
  }
  const int cr = (lane >> 4) * 4;
  const int cc = lane & 15;
#pragma unroll
  for (int mi = 0; mi < 4; ++mi)
#pragma unroll
    for (int ni = 0; ni < 4; ++ni) {
#pragma unroll
      for (int r = 0; r < 4; ++r) {
        const int row = m0 + wm * 64 + mi * 16 + cr + r;      // qrow in [0,256)
        const int ch = (row >> 3) * 24 + (row & 7);           // -> channel
        Cb[(size_t)ch * N_PIX + n0 + wn * 64 + ni * 16 + cc] = (f16)acc[mi][ni][r];
      }
    }
}

// ---------------------------------------------------------------------------
// k_gemmkv: qkv K/V-rows = A[512][256] * Bh^T, 1-term f16, BK=64.
// (k/v tolerate 1-term: no divide-amplification — that is q-only.)
// ---------------------------------------------------------------------------
__global__ __launch_bounds__(256) void k_gemmkv(const f16* __restrict__ A,
                                                const f16* __restrict__ B,
                                                f16* __restrict__ C,
                                                int M, int K) {
  __shared__ f16 sm[2][16 * 1024];
  const int t = threadIdx.x;
  const int lane = t & 63;
  const int w = t >> 6;

  const int per = gridDim.x >> 3;
  const int swz = (blockIdx.x & 7) * per + (blockIdx.x >> 3);
  const int mtiles = M >> 7;  // 4
  const int mt = swz % mtiles;
  const int rest = swz / mtiles;
  const int nt = rest & 31;
  const size_t bz = rest >> 5;
  const int m0 = mt * 128;
  const int n0 = nt * 128;

  const f16* Bb = B + bz * (size_t)N_PIX * K;
  f16* Cb = C + bz * (size_t)TD3 * N_PIX;

  f32x4 acc[4][4];
#pragma unroll
  for (int i = 0; i < 4; ++i)
#pragma unroll
    for (int j = 0; j < 4; ++j) acc[i][j] = (f32x4){0.f, 0.f, 0.f, 0.f};

  const int wm = w >> 1, wn = w & 1;
  const int fr2 = lane >> 3;
  const int fko = (lane & 7) * 8;
  const f16* gsrc[4][2];
  int sslot[4][2];
#pragma unroll
  for (int i = 0; i < 4; ++i) {
    const int s = w + i * 4;
    const int frag = s & 7;
    const f16* base = (s < 8) ? A : Bb;
    const int row0 = (s < 8) ? m0 : n0;
#pragma unroll
    for (int j = 0; j < 2; ++j) {
      gsrc[i][j] = base + (size_t)(row0 + frag * 16 + j * 8 + fr2) * K + fko;
      sslot[i][j] = s * 1024 + j * 512;
    }
  }

#pragma unroll
  for (int i = 0; i < 4; ++i)
#pragma unroll
    for (int j = 0; j < 2; ++j)
      __builtin_amdgcn_global_load_lds(
          (const __attribute__((address_space(1))) unsigned int*)gsrc[i][j],
          (__attribute__((address_space(3))) unsigned int*)&sm[0][sslot[i][j]], 16, 0, 0);

  const int ntk = K / 64;  // 4
  int cur = 0;
  for (int tt = 0; tt < ntk; ++tt) {
    if (tt + 1 < ntk) {
#pragma unroll
      for (int i = 0; i < 4; ++i)
#pragma unroll
        for (int j = 0; j < 2; ++j)
          __builtin_amdgcn_global_load_lds(
              (const __attribute__((address_space(1))) unsigned int*)(gsrc[i][j] + (tt + 1) * 64),
              (__attribute__((address_space(3))) unsigned int*)&sm[cur ^ 1][sslot[i][j]], 16, 0, 0);
      asm volatile("s_waitcnt vmcnt(8)" ::: "memory");
    } else {
      asm volatile("s_waitcnt vmcnt(0)" ::: "memory");
    }
    __builtin_amdgcn_s_barrier();
    const f16* smb = sm[cur];
    const int fb = (lane & 15) * 64 + (lane >> 4) * 8;
    half8 av[4][2], bv[4][2];
#pragma unroll
    for (int mi = 0; mi < 4; ++mi)
#pragma unroll
      for (int kk = 0; kk < 2; ++kk)
        av[mi][kk] = *(const half8*)&smb[(wm * 4 + mi) * 1024 + fb + kk * 32];
#pragma unroll
    for (int ni = 0; ni < 4; ++ni)
#pragma unroll
      for (int kk = 0; kk < 2; ++kk)
        bv[ni][kk] = *(const half8*)&smb[(8 + wn * 4 + ni) * 1024 + fb + kk * 32];
#pragma unroll
    for (int kk = 0; kk < 2; ++kk)
#pragma unroll
      for (int mi = 0; mi < 4; ++mi)
#pragma unroll
        for (int ni = 0; ni < 4; ++ni)
          acc[mi][ni] = __builtin_amdgcn_mfma_f32_16x16x32_f16(av[mi][kk], bv[ni][kk], acc[mi][ni], 0, 0, 0);
    __builtin_amdgcn_s_barrier();
    cur ^= 1;
  }
  const int cr = (lane >> 4) * 4;
  const int cc = lane & 15;
#pragma unroll
  for (int mi = 0; mi < 4; ++mi)
#pragma unroll
    for (int ni = 0; ni < 4; ++ni) {
#pragma unroll
      for (int r = 0; r < 4; ++r) {
        const int row = m0 + wm * 64 + mi * 16 + cr + r;      // kvrow in [0,512)
        const int ch = (row >> 4) * 24 + 8 + (row & 15);      // -> channel
        Cb[(size_t)ch * N_PIX + n0 + wn * 64 + ni * 16 + cc] = (f16)acc[mi][ni][r];
      }
    }
}

// ---------------------------------------------------------------------------
// k_gemm1: C = A[M][K] * B[b][4096][K]^T, single-f16 MFMA (proj).
// ---------------------------------------------------------------------------
template <typename OutT>
__global__ __launch_bounds__(256) void k_gemm1(const f16* __restrict__ A,
                                               const f16* __restrict__ B,
                                               OutT* __restrict__ C,
                                               int M, int K) {
  __shared__ f16 sm[2][16 * 512];
  const int t = threadIdx.x;
  const int lane = t & 63;
  const int w = t >> 6;
  const int n0 = blockIdx.x * 128;
  const int m0 = blockIdx.y * 128;
  const size_t bz = blockIdx.z;
  const f16* Bb = B + bz * (size_t)N_PIX * K;
  OutT* Cb = C + bz * (size_t)M * N_PIX;

  f32x4 acc[4][4];
#pragma unroll
  for (int i = 0; i < 4; ++i)
#pragma unroll
    for (int j = 0; j < 4; ++j) acc[i][j] = (f32x4){0.f, 0.f, 0.f, 0.f};

  const int wm = w >> 1, wn = w & 1;
  const int fr = lane & 15;
  const int fk = (lane >> 4) * 8;

  const f16* gsrc[4];
  int sslot[4];
#pragma unroll
  for (int i = 0; i < 4; ++i) {
    const int s = w + i * 4;
    const int frag = s & 7;
    const f16* base;
    int row0;
    if (s < 8) {
      base = A; row0 = m0;
    } else {
      base = Bb; row0 = n0;
    }
    gsrc[i] = base + (size_t)(row0 + frag * 16 + fr) * K + fk;
    sslot[i] = s * 512;
  }

#pragma unroll
  for (int i = 0; i < 4; ++i)
    __builtin_amdgcn_global_load_lds(
        (const __attribute__((address_space(1))) unsigned int*)gsrc[i],
        (__attribute__((address_space(3))) unsigned int*)&sm[0][sslot[i]], 16, 0, 0);

  const int nt = K / 32;
  int cur = 0;
  for (int tt = 0; tt < nt; ++tt) {
    if (tt + 1 < nt) {
#pragma unroll
      for (int i = 0; i < 4; ++i)
        __builtin_amdgcn_global_load_lds(
            (const __attribute__((address_space(1))) unsigned int*)(gsrc[i] + (tt + 1) * 32),
            (__attribute__((address_space(3))) unsigned int*)&sm[cur ^ 1][sslot[i]], 16, 0, 0);
      asm volatile("s_waitcnt vmcnt(4)" ::: "memory");
    } else {
      asm volatile("s_waitcnt vmcnt(0)" ::: "memory");
    }
    __builtin_amdgcn_s_barrier();
    const f16* smb = sm[cur];
    half8 av[4], bv[4];
#pragma unroll
    for (int mi = 0; mi < 4; ++mi) av[mi] = *(const half8*)&smb[(wm * 4 + mi) * 512 + lane * 8];
#pragma unroll
    for (int ni = 0; ni < 4; ++ni) bv[ni] = *(const half8*)&smb[(8 + wn * 4 + ni) * 512 + lane * 8];
#pragma unroll
    for (int mi = 0; mi < 4; ++mi)
#pragma unroll
      for (int ni = 0; ni < 4; ++ni)
        acc[mi][ni] = __builtin_amdgcn_mfma_f32_16x16x32_f16(av[mi], bv[ni], acc[mi][ni], 0, 0, 0);
    __builtin_amdgcn_s_barrier();
    cur ^= 1;
  }
  const int cr = (lane >> 4) * 4;
  const int cc = lane & 15;
#pragma unroll
  for (int mi = 0; mi < 4; ++mi)
#pragma unroll
    for (int ni = 0; ni < 4; ++ni) {
      OutT* p = Cb + (size_t)(m0 + wm * 64 + mi * 16 + cr) * N_PIX + n0 + wn * 64 + ni * 16 + cc;
#pragma unroll
      for (int r = 0; r < 4; ++r) p[(size_t)r * N_PIX] = (OutT)acc[mi][ni][r];
    }
}

// ---------------------------------------------------------------------------
// k_dw: depthwise 5x5 (split form — fusion regressed twice: R3, R10).
// ---------------------------------------------------------------------------
__global__ __launch_bounds__(256) void k_dw(const f16* __restrict__ qkv,
                                            const float* __restrict__ wdw,
                                            f16* __restrict__ dw) {
  __shared__ float sin_[68][72];
  const int t = threadIdx.x;
  const int bc = blockIdx.x;
  const int ch = bc % TD3;
  const f16* src = qkv + (size_t)bc * N_PIX;

  for (int i = t; i < 68 * 72 / 4; i += 256) ((f32x4*)sin_)[i] = (f32x4){0.f, 0.f, 0.f, 0.f};
  float wreg[25];
#pragma unroll
  for (int i = 0; i < 25; ++i) wreg[i] = wdw[(size_t)ch * 25 + i];
  __syncthreads();
  for (int i = t; i < 512; i += 256) {
    const int r = i >> 3, c8 = (i & 7) * 8;
    const half8 p = *(const half8*)(src + r * 64 + c8);
    f32x4 lo = {(float)p[0], (float)p[1], (float)p[2], (float)p[3]};
    f32x4 hi = {(float)p[4], (float)p[5], (float)p[6], (float)p[7]};
    *(f32x4*)&sin_[r + 2][c8 + 4] = lo;
    *(f32x4*)&sin_[r + 2][c8 + 8] = hi;
  }
  __syncthreads();

  const int c = t & 63;
  const int rg = t >> 6;
  const int r0 = rg * 16;
  float win[5][5];
#pragma unroll
  for (int r = 0; r < 4; ++r)
#pragma unroll
    for (int j = 0; j < 5; ++j) win[r][j] = sin_[r0 + r][c + 2 + j];
#pragma unroll
  for (int orow = 0; orow < 16; ++orow) {
    const int slot = (orow + 4) % 5;
#pragma unroll
    for (int j = 0; j < 5; ++j) win[slot][j] = sin_[r0 + orow + 4][c + 2 + j];
    float s = 0.f;
#pragma unroll
    for (int dr = 0; dr < 5; ++dr) {
      const int rs = (orow + dr) % 5;
#pragma unroll
      for (int dc = 0; dc < 5; ++dc) s = fmaf(win[rs][dc], wreg[dr * 5 + dc], s);
    }
    dw[(size_t)bc * N_PIX + (r0 + orow) * 64 + c] = (f16)s;
  }
}

// ---------------------------------------------------------------------------
// k_pw: grouped pointwise 8->8, streaming.
// ---------------------------------------------------------------------------
__global__ __launch_bounds__(256) void k_pw(const f16* __restrict__ dw,
                                            const float* __restrict__ wpw,
                                            f16* __restrict__ agg) {
  const int t = threadIdx.x;
  const int q = blockIdx.x;
  const int bg = blockIdx.y;
  const int g = bg % 96;
  float wp[64];
#pragma unroll
  for (int i = 0; i < 64; ++i) wp[i] = wpw[(size_t)g * 64 + i];
  const size_t base = ((size_t)(bg / 96) * TD3 + g * 8) * N_PIX + q * 1024;
  const int px0 = t * 4;
  float dv[8][4];
#pragma unroll
  for (int ic = 0; ic < 8; ++ic) {
    const f16x4 v = *(const f16x4*)(dw + base + (size_t)ic * N_PIX + px0);
#pragma unroll
    for (int j = 0; j < 4; ++j) dv[ic][j] = (float)v[j];
  }
#pragma unroll
  for (int oc = 0; oc < 8; ++oc) {
    f16x4 o;
#pragma unroll
    for (int j = 0; j < 4; ++j) {
      float s = 0.f;
#pragma unroll
      for (int ic = 0; ic < 8; ++ic) s = fmaf(dv[ic][j], wp[oc * 8 + ic], s);
      o[j] = (f16)s;
    }
    *(f16x4*)(agg + base + (size_t)oc * N_PIX + px0) = o;
  }
}

// ---------------------------------------------------------------------------
// k_kv: kv[b][g][72] = sum_n relu(k)·vext, one block per (g,b), fp32 acc.
// R13: KV_CHUNKS=1 (4x fewer wave-reduces) + split-work xor butterfly:
// fold xor-32 on all 72 accs, then each 32-lane half finalizes 36 accs
// (252 cross-lane ops vs 432). Association tree is bit-identical to the
// old shfl_down tree (commutative pairwise sums, same pairing).
// ---------------------------------------------------------------------------
__global__ __launch_bounds__(256, 1) void k_kv(const f16* __restrict__ qkv,
                                               const f16* __restrict__ agg,
                                               float* __restrict__ kvbuf) {
  const int t = threadIdx.x;
  const int g = blockIdx.x;
  const int b = blockIdx.y;
  const f16* src = (g < 32) ? qkv : agg;
  const int base = (g & 31) * 24;
  const f16* kc = src + ((size_t)b * TD3 + base + 8) * N_PIX;
  const f16* vc = src + ((size_t)b * TD3 + base + 16) * N_PIX;

  float acc[72];
#pragma unroll
  for (int i = 0; i < 72; i++) acc[i] = 0.f;

  for (int i = 0; i < N_PIX / 256; i++) {  // 16 iterations
    const int n = t + i * 256;
    float kd[8], ve[8];
#pragma unroll
    for (int d = 0; d < 8; d++) kd[d] = fmaxf((float)kc[(size_t)d * N_PIX + n], 0.f);
#pragma unroll
    for (int e = 0; e < 8; e++) ve[e] = (float)vc[(size_t)e * N_PIX + n];
#pragma unroll
    for (int d = 0; d < 8; d++) {
#pragma unroll
      for (int e = 0; e < 8; e++) acc[d * 9 + e] = fmaf(kd[d], ve[e], acc[d * 9 + e]);
      acc[d * 9 + 8] += kd[d];
    }
  }

  const int lane = t & 63, wv = t >> 6;
  // fold across the 32-lane halves (all 72 accs)
#pragma unroll
  for (int i = 0; i < 72; i++) acc[i] += __shfl_xor(acc[i], 32, 64);
  // split: lanes <32 finalize accs 0..35, lanes >=32 finalize 36..71
  const int hi = lane >> 5;  // 0 or 1
  float r[36];
#pragma unroll
  for (int i = 0; i < 36; i++) r[i] = hi ? acc[36 + i] : acc[i];
#pragma unroll
  for (int off = 16; off >= 1; off >>= 1) {
#pragma unroll
    for (int i = 0; i < 36; i++) r[i] += __shfl_xor(r[i], off, 64);
  }
  __shared__ float red[4][72];
  if (lane == 0 || lane == 32) {
#pragma unroll
    for (int i = 0; i < 36; i++) red[wv][hi * 36 + i] = r[i];
  }
  __syncthreads();
  if (t < 72) {
    const float s = red[0][t] + red[1][t] + red[2][t] + red[3][t];
    kvbuf[((size_t)b * N_G + g) * 72 + t] = s;
  }
}

// ---------------------------------------------------------------------------
// k_att: att^T[b][4096][512] f16 (kvbuf now holds final sums).
// ---------------------------------------------------------------------------
__global__ __launch_bounds__(256) void k_att(const f16* __restrict__ qkvh,
                                             const f16* __restrict__ aggh,
                                             const float* __restrict__ kvbuf,
                                             f16* __restrict__ atth) {
  __shared__ float skv[N_G * 72];
  __shared__ f16 sa[512][34];
  const int t = threadIdx.x;
  const int n0 = blockIdx.x * 32;
  const size_t b = blockIdx.y;
  for (int i = t; i < N_G * 72; i += 256) skv[i] = kvbuf[b * (N_G * 72) + i];
  __syncthreads();
  const int px = t & 31, gq = t >> 5;
#pragma unroll
  for (int gi = 0; gi < 8; ++gi) {
    const int g = gq * 8 + gi;
    const f16* src = (g < 32) ? qkvh : aggh;
    const int base = (g & 31) * 24;
    const f16* qc = src + ((size_t)b * TD3 + base) * N_PIX + n0 + px;
    float num[8] = {0.f, 0.f, 0.f, 0.f, 0.f, 0.f, 0.f, 0.f};
    float den = 0.f;
#pragma unroll
    for (int d = 0; d < 8; ++d) {
      const float qd = fmaxf((float)qc[(size_t)d * N_PIX], 0.f);
      const float* kvg = &skv[g * 72 + d * 9];
#pragma unroll
      for (int e = 0; e < 8; ++e) num[e] = fmaf(qd, kvg[e], num[e]);
      den = fmaf(qd, kvg[8], den);
    }
    const float rd = 1.f / (den + 1e-15f);
#pragma unroll
    for (int e = 0; e < 8; ++e) sa[g * 8 + e][px] = (f16)(num[e] * rd);
  }
  __syncthreads();
  f16* dst = atth + (b * N_PIX + n0) * 512;
  for (int i = 0; i < 64; ++i) {
    const int idx = t + i * 256;
    dst[idx] = sa[idx & 511][idx >> 9];
  }
}

// ---------------------------------------------------------------------------
extern "C" void kernel_launch(void* const* d_in, const int* in_sizes, int n_in,
                              void* d_out, int out_size, void* d_ws, size_t ws_size,
                              hipStream_t stream) {
  const float* x = (const float*)d_in[0];
  const float* w_qkv = (const float*)d_in[1];
  const float* w_dw = (const float*)d_in[2];
  const float* w_pw = (const float*)d_in[3];
  const float* w_proj = (const float*)d_in[4];
  float* out = (float*)d_out;

  char* ws = (char*)d_ws;
  size_t off = 0;
  f16* qkvh = (f16*)(ws + off); off += (size_t)N_B * TD3 * N_PIX * 2;  // 50.3 MB
  f16* aggh = (f16*)(ws + off); off += (size_t)N_B * TD3 * N_PIX * 2;  // 50.3 MB
  float* kvbuf = (float*)(ws + off); off += (size_t)N_B * N_G * 72 * 4;
  f16* wqq_h = (f16*)(ws + off); off += (size_t)256 * C_IN * 2;
  f16* wqq_l = (f16*)(ws + off); off += (size_t)256 * C_IN * 2;
  f16* wqkv = (f16*)(ws + off); off += (size_t)512 * C_IN * 2;
  f16* wph = (f16*)(ws + off); off += (size_t)C_OUT * 512 * 2;
  // union region (disjoint lifetimes): xT(hi,lo) -> dwbuf -> attT(single)
  f16* xTh = (f16*)(ws + off);
  f16* xTl = xTh + (size_t)N_B * N_PIX * C_IN;
  f16* dwbuf = (f16*)(ws + off);
  f16* atth = (f16*)(ws + off);

  const int ncvt = (TD3 * C_IN + C_OUT * 512 + 255) / 256;
  k_cvtw<<<dim3(ncvt), 256, 0, stream>>>(w_qkv, w_proj, wqq_h, wqq_l, wqkv, wph);
  k_xT<<<dim3(N_PIX / 64, C_IN / 64, N_B), 256, 0, stream>>>(x, xTh, xTl);
  k_gemmq<<<dim3(2 * 32 * N_B), 256, 0, stream>>>(
      wqq_h, wqq_l, xTh, xTl, qkvh, 256, C_IN);
  k_gemmkv<<<dim3(4 * 32 * N_B), 256, 0, stream>>>(
      wqkv, xTh, qkvh, 512, C_IN);
  k_dw<<<dim3(N_B * TD3), 256, 0, stream>>>(qkvh, w_dw, dwbuf);
  k_pw<<<dim3(4, N_B * 96), 256, 0, stream>>>(dwbuf, w_pw, aggh);
  k_kv<<<dim3(N_G, N_B), 256, 0, stream>>>(qkvh, aggh, kvbuf);
  k_att<<<dim3(N_PIX / 32, N_B), 256, 0, stream>>>(qkvh, aggh, kvbuf, atth);
  k_gemm1<float><<<dim3(N_PIX / 128, C_OUT / 128, N_B), 256, 0, stream>>>(
      wph, atth, out, C_OUT, 512);
}